// Round 1
// baseline (1054.391 us; speedup 1.0000x reference)
//
#include <hip/hip_runtime.h>
#include <hip/hip_bf16.h>
#include <math.h>

// Problem constants
#define B_  8
#define T_  2048
#define C_  128
#define H_  4
#define DH_ 32
#define BH_ (B_ * H_)           // 32
#define NTOK (B_ * T_)          // 16384
#define SCALE_ 0.17677669529663687f  // 1/sqrt(32)

// ---------------------------------------------------------------------------
// Kernel 1: QKV projection. x[NTOK,128] @ Wqkv[128,384] + bqkv -> Q,K,V in
// [BH, T, 32] layout (Q pre-scaled by 1/sqrt(Dh)).
// grid: NTOK/32 = 512 blocks, block: 384 threads (one col each, 32 rows).
// ---------------------------------------------------------------------------
__global__ __launch_bounds__(384)
void qkv_proj(const float* __restrict__ x, const float* __restrict__ Wqkv,
              const float* __restrict__ bqkv,
              float* __restrict__ Q, float* __restrict__ K, float* __restrict__ V) {
    __shared__ float xs[32 * 128];
    const int tid = threadIdx.x;
    const long rowbase = (long)blockIdx.x * 32;

    // stage 32 rows of x (4096 floats) as float4
    const float4* xsrc = (const float4*)(x + rowbase * 128);
    float4* xdst = (float4*)xs;
    for (int i = tid; i < 1024; i += 384) xdst[i] = xsrc[i];
    __syncthreads();

    const int col = tid;  // 0..383
    float acc[32];
#pragma unroll
    for (int r = 0; r < 32; ++r) acc[r] = 0.f;

    for (int k = 0; k < 128; k += 4) {
        const float w0 = Wqkv[(k + 0) * 384 + col];
        const float w1 = Wqkv[(k + 1) * 384 + col];
        const float w2 = Wqkv[(k + 2) * 384 + col];
        const float w3 = Wqkv[(k + 3) * 384 + col];
#pragma unroll
        for (int r = 0; r < 32; ++r) {
            const float4 xv = *(const float4*)&xs[r * 128 + k];  // wave-uniform broadcast
            acc[r] = fmaf(xv.x, w0, acc[r]);
            acc[r] = fmaf(xv.y, w1, acc[r]);
            acc[r] = fmaf(xv.z, w2, acc[r]);
            acc[r] = fmaf(xv.w, w3, acc[r]);
        }
    }

    const float bias = bqkv[col];
    const int which = col >> 7;     // 0=Q, 1=K, 2=V
    const int c = col & 127;
    const int h = c >> 5;
    const int d = c & 31;
    float* dst = (which == 0) ? Q : ((which == 1) ? K : V);
    const float scale = (which == 0) ? SCALE_ : 1.0f;

#pragma unroll
    for (int r = 0; r < 32; ++r) {
        const long row = rowbase + r;           // global token index b*T + t
        const long bb = row >> 11;              // /2048
        const long t  = row & 2047;
        dst[((bb * H_ + h) * (long)T_ + t) * DH_ + d] = (acc[r] + bias) * scale;
    }
}

// ---------------------------------------------------------------------------
// Kernel 2: flash attention (fp32). One block = one (b,h) x 16 q-rows.
// 4 waves, 4 q-rows per wave. s-tile = 64 (one lane per s).
// K tile in registers, V tile in LDS, Q in LDS (broadcast reads).
// Output written to O = d_out as [B, T, 128] (scratch; out_proj finishes).
// ---------------------------------------------------------------------------
#define QTILE 16
#define STILE 64

__global__ __launch_bounds__(256)
void attn(const float* __restrict__ Q, const float* __restrict__ K,
          const float* __restrict__ V, float* __restrict__ O) {
    __shared__ float vs[STILE * 32];   // V tile, [s][d] -- conflict-free reads
    __shared__ float qs[QTILE * 32];   // Q rows (broadcast reads)

    const int bh = blockIdx.y;         // 0..31
    const int b  = bh >> 2;
    const int h  = bh & 3;
    const int qbase = blockIdx.x * QTILE;

    const float* Qp = Q + (long)bh * T_ * DH_;
    const float* Kp = K + (long)bh * T_ * DH_;
    const float* Vp = V + (long)bh * T_ * DH_;

    const int tid  = threadIdx.x;
    const int wave = tid >> 6;
    const int lane = tid & 63;
    const int half = lane >> 5;   // 0: s 0..31 of tile, 1: s 32..63
    const int dd   = lane & 31;   // output dim owned for PV accumulation

    // stage Q rows
    for (int i = tid; i < QTILE * 32; i += 256) qs[i] = Qp[(long)qbase * 32 + i];

    float m[4], l[4], acc[4];
    int qr[4];
#pragma unroll
    for (int r = 0; r < 4; ++r) {
        m[r] = -INFINITY; l[r] = 0.f; acc[r] = 0.f;
        qr[r] = qbase + wave * 4 + r;
    }
    const int smax = qbase + QTILE;   // exclusive upper bound on needed s

    for (int sbase = 0; sbase < smax; sbase += STILE) {
        __syncthreads();  // previous tile's vs reads done (also covers qs on iter 0)
        // stage V tile: 2048 floats
        for (int i = tid; i < STILE * 32; i += 256) vs[i] = Vp[(long)sbase * 32 + i];
        // this lane's K row into registers
        float kreg[32];
        const int srow = sbase + lane;
        const float4* kp4 = (const float4*)(Kp + (long)srow * 32);
#pragma unroll
        for (int i = 0; i < 8; ++i) {
            const float4 kv = kp4[i];
            kreg[4 * i + 0] = kv.x; kreg[4 * i + 1] = kv.y;
            kreg[4 * i + 2] = kv.z; kreg[4 * i + 3] = kv.w;
        }
        __syncthreads();

#pragma unroll
        for (int r = 0; r < 4; ++r) {
            if (sbase > qr[r]) continue;   // wave-uniform skip
            // QK dot for this lane's s
            float sc = 0.f;
#pragma unroll
            for (int d4 = 0; d4 < 8; ++d4) {
                const float4 qv = *(const float4*)&qs[(wave * 4 + r) * 32 + d4 * 4];
                sc = fmaf(qv.x, kreg[4 * d4 + 0], sc);
                sc = fmaf(qv.y, kreg[4 * d4 + 1], sc);
                sc = fmaf(qv.z, kreg[4 * d4 + 2], sc);
                sc = fmaf(qv.w, kreg[4 * d4 + 3], sc);
            }
            const bool valid = (srow <= qr[r]);
            // tile max over 64 lanes
            float tmax = valid ? sc : -INFINITY;
#pragma unroll
            for (int off = 32; off >= 1; off >>= 1)
                tmax = fmaxf(tmax, __shfl_xor(tmax, off));
            const float newm = fmaxf(m[r], tmax);
            const float p = valid ? __expf(sc - newm) : 0.f;
            float psum = p;
#pragma unroll
            for (int off = 32; off >= 1; off >>= 1)
                psum += __shfl_xor(psum, off);
            const float corr = (m[r] == -INFINITY) ? 0.f : __expf(m[r] - newm);
            m[r] = newm;
            l[r] = l[r] * corr + psum;
            acc[r] *= corr;
            // PV: this lane accumulates dim dd over its half's 32 s values
#pragma unroll
            for (int j = 0; j < 32; ++j) {
                const float pj = __shfl(p, half * 32 + j);
                acc[r] = fmaf(pj, vs[(half * 32 + j) * 32 + dd], acc[r]);
            }
        }
    }

    // combine the two s-halves and write
#pragma unroll
    for (int r = 0; r < 4; ++r) {
        const float other = __shfl_xor(acc[r], 32);
        const float tot = acc[r] + other;
        const float o = tot / l[r];
        if (half == 0) {
            const long row = (long)b * T_ + qr[r];
            O[row * C_ + h * DH_ + dd] = o;
        }
    }
}

// ---------------------------------------------------------------------------
// Kernel 3: output projection, in place on O = d_out.
// out[row] = attn[row] @ Wout + bout. Each block owns 32 rows: read them into
// LDS first, sync, then compute+overwrite (block-local, safe).
// grid: 512, block: 256 (col = tid&127, two 16-row groups).
// ---------------------------------------------------------------------------
__global__ __launch_bounds__(256)
void out_proj(float* __restrict__ O, const float* __restrict__ Wout,
              const float* __restrict__ bout) {
    __shared__ float xs[32 * 128];
    const long rowbase = (long)blockIdx.x * 32;
    const int tid = threadIdx.x;

    const float4* src = (const float4*)(O + rowbase * 128);
    float4* xdst = (float4*)xs;
    for (int i = tid; i < 1024; i += 256) xdst[i] = src[i];
    __syncthreads();

    const int col = tid & 127;
    const int rhalf = tid >> 7;   // 0 or 1 -> rows rhalf*16 .. rhalf*16+15
    float acc[16];
#pragma unroll
    for (int r = 0; r < 16; ++r) acc[r] = 0.f;

    for (int k = 0; k < 128; k += 4) {
        const float w0 = Wout[(k + 0) * 128 + col];
        const float w1 = Wout[(k + 1) * 128 + col];
        const float w2 = Wout[(k + 2) * 128 + col];
        const float w3 = Wout[(k + 3) * 128 + col];
#pragma unroll
        for (int r = 0; r < 16; ++r) {
            const float4 xv = *(const float4*)&xs[(rhalf * 16 + r) * 128 + k];
            acc[r] = fmaf(xv.x, w0, acc[r]);
            acc[r] = fmaf(xv.y, w1, acc[r]);
            acc[r] = fmaf(xv.z, w2, acc[r]);
            acc[r] = fmaf(xv.w, w3, acc[r]);
        }
    }

    const float bias = bout[col];
#pragma unroll
    for (int r = 0; r < 16; ++r) {
        O[(rowbase + rhalf * 16 + r) * C_ + col] = acc[r] + bias;
    }
}

// ---------------------------------------------------------------------------
extern "C" void kernel_launch(void* const* d_in, const int* in_sizes, int n_in,
                              void* d_out, int out_size, void* d_ws, size_t ws_size,
                              hipStream_t stream) {
    const float* x    = (const float*)d_in[0];
    const float* Wqkv = (const float*)d_in[1];
    const float* bqkv = (const float*)d_in[2];
    const float* Wout = (const float*)d_in[3];
    const float* bout = (const float*)d_in[4];
    float* out = (float*)d_out;

    const size_t per = (size_t)BH_ * T_ * DH_;   // 2,097,152 floats = 8 MB
    float* Q = (float*)d_ws;
    float* K = Q + per;
    float* V = K + per;

    qkv_proj<<<NTOK / 32, 384, 0, stream>>>(x, Wqkv, bqkv, Q, K, V);

    dim3 g2(T_ / QTILE, BH_);
    attn<<<g2, 256, 0, stream>>>(Q, K, V, out);

    out_proj<<<NTOK / 32, 256, 0, stream>>>(out, Wout, bout);
}

// Round 2
// 162.178 us; speedup vs baseline: 6.5014x; 6.5014x over previous
//
#include <hip/hip_runtime.h>
#include <hip/hip_bf16.h>
#include <math.h>

// Problem constants
#define B_  8
#define T_  2048
#define C_  128
#define H_  4
#define DH_ 32
#define BH_ 32
#define NTOK 16384
// (1/sqrt(32)) * log2(e): scores come out in log2 domain -> softmax via exp2
#define QSCALE_ 0.25503486f

typedef __attribute__((ext_vector_type(8))) __bf16 bfrag;       // 4 VGPRs, MFMA A/B
typedef __attribute__((ext_vector_type(4))) float f32x4;        // MFMA C/D
typedef __attribute__((ext_vector_type(2))) unsigned int u32x2;
typedef __attribute__((ext_vector_type(4))) unsigned int u32x4;

__device__ __forceinline__ unsigned int pack2bf(float a, float b) {
    unsigned int ua = __float_as_uint(a);
    unsigned int ub = __float_as_uint(b);
    ua += 0x7fffu + ((ua >> 16) & 1u);   // RNE to bf16
    ub += 0x7fffu + ((ub >> 16) & 1u);
    return (ua >> 16) | (ub & 0xffff0000u);
}

// ---------------------------------------------------------------------------
// Kernel 1: QKV projection (fp32 math) -> Qb,Kb bf16 [BH][T][32] (Q pre-scaled
// by 1/sqrt(Dh)*log2e), Vt bf16 [BH][32][T] (transposed for MFMA B-fragments).
// ---------------------------------------------------------------------------
__global__ __launch_bounds__(384)
void qkv_proj(const float* __restrict__ x, const float* __restrict__ Wqkv,
              const float* __restrict__ bqkv,
              __hip_bfloat16* __restrict__ Qb, __hip_bfloat16* __restrict__ Kb,
              __hip_bfloat16* __restrict__ Vt) {
    __shared__ float xs[32 * 128];
    const int tid = threadIdx.x;
    const long rowbase = (long)blockIdx.x * 32;

    const float4* xsrc = (const float4*)(x + rowbase * 128);
    float4* xdst = (float4*)xs;
    for (int i = tid; i < 1024; i += 384) xdst[i] = xsrc[i];
    __syncthreads();

    const int col = tid;  // 0..383
    float acc[32];
#pragma unroll
    for (int r = 0; r < 32; ++r) acc[r] = 0.f;

    for (int k = 0; k < 128; k += 4) {
        const float w0 = Wqkv[(k + 0) * 384 + col];
        const float w1 = Wqkv[(k + 1) * 384 + col];
        const float w2 = Wqkv[(k + 2) * 384 + col];
        const float w3 = Wqkv[(k + 3) * 384 + col];
#pragma unroll
        for (int r = 0; r < 32; ++r) {
            const float4 xv = *(const float4*)&xs[r * 128 + k];
            acc[r] = fmaf(xv.x, w0, acc[r]);
            acc[r] = fmaf(xv.y, w1, acc[r]);
            acc[r] = fmaf(xv.z, w2, acc[r]);
            acc[r] = fmaf(xv.w, w3, acc[r]);
        }
    }

    const float bias = bqkv[col];
    const int which = col >> 7;     // 0=Q, 1=K, 2=V
    const int c = col & 127;
    const int h = c >> 5;
    const int d = c & 31;

#pragma unroll
    for (int r = 0; r < 32; ++r) {
        const long row = rowbase + r;
        const long bb = row >> 11;
        const long t  = row & 2047;
        const long bh = bb * H_ + h;
        const float val = acc[r] + bias;
        if (which == 0)      Qb[(bh * T_ + t) * DH_ + d] = __float2bfloat16(val * QSCALE_);
        else if (which == 1) Kb[(bh * T_ + t) * DH_ + d] = __float2bfloat16(val);
        else                 Vt[(bh * DH_ + d) * T_ + t] = __float2bfloat16(val);
    }
}

// ---------------------------------------------------------------------------
// Kernel 2: MFMA flash attention.
// Per wave: 16 q-rows, s-tiles of 64. S^T = mfma(K,Q) (lane owns q = lane&15);
// softmax in-register (2 shfl_xor); P -> LDS (bf16, padded) -> A/B frag;
// O^T = mfma(V^T, P^T) keeps the same q-per-lane ownership so rescale is local.
// No __syncthreads: waves fully independent, per-wave LDS P buffer.
// ---------------------------------------------------------------------------
#define PSTRU 36   // uint stride per P row (64 bf16 + 8 pad)

__global__ __launch_bounds__(256)
void attn_mfma(const __hip_bfloat16* __restrict__ Qb,
               const __hip_bfloat16* __restrict__ Kb,
               const __hip_bfloat16* __restrict__ Vt,
               float* __restrict__ O) {
    __shared__ unsigned int plds[4][16 * PSTRU];

    const int bh = blockIdx.y;      // 0..31
    const int b  = bh >> 2, h = bh & 3;
    const int tid  = threadIdx.x;
    const int w    = tid >> 6;
    const int lane = tid & 63;
    const int qi   = lane & 15;
    const int grp  = lane >> 4;     // 0..3
    const int qbase = blockIdx.x * 64 + w * 16;
    const int q = qbase + qi;

    const __hip_bfloat16* Qp = Qb + (size_t)bh * T_ * DH_;
    const __hip_bfloat16* Kp = Kb + (size_t)bh * T_ * DH_;
    const __hip_bfloat16* Vp = Vt + (size_t)bh * DH_ * T_;

    const bfrag qfrag = *(const bfrag*)(Qp + q * DH_ + grp * 8);

    const f32x4 zero = {0.f, 0.f, 0.f, 0.f};
    f32x4 acc0 = zero, acc1 = zero;
    float m = -INFINITY, l = 0.f;

    unsigned int* pbuf = plds[w];
    const int qmax = qbase + 15;

    for (int s0 = 0; s0 <= qmax; s0 += 64) {
        // ---- QK^T (transposed): st[sb] covers s = s0+sb*16 .. +15, q = qbase+0..15
        f32x4 st[4];
#pragma unroll
        for (int sb = 0; sb < 4; ++sb) {
            const bfrag kf = *(const bfrag*)(Kp + (s0 + sb * 16 + qi) * DH_ + grp * 8);
            st[sb] = __builtin_amdgcn_mfma_f32_16x16x32_bf16(kf, qfrag, zero, 0, 0, 0);
        }
        // ---- causal mask (only the diagonal band step needs it)
        if (s0 + 63 > qbase) {
#pragma unroll
            for (int sb = 0; sb < 4; ++sb)
#pragma unroll
                for (int r = 0; r < 4; ++r)
                    if (s0 + sb * 16 + grp * 4 + r > q) st[sb][r] = -INFINITY;
        }
        // ---- online softmax (lane owns one q; lanes {q,q+16,q+32,q+48} share it)
        float mx = m;
#pragma unroll
        for (int sb = 0; sb < 4; ++sb)
            mx = fmaxf(mx, fmaxf(fmaxf(st[sb][0], st[sb][1]), fmaxf(st[sb][2], st[sb][3])));
        mx = fmaxf(mx, __shfl_xor(mx, 16));
        mx = fmaxf(mx, __shfl_xor(mx, 32));
        const float corr = exp2f(m - mx);
        m = mx;
        float nl = 0.f;
#pragma unroll
        for (int sb = 0; sb < 4; ++sb) {
            const float p0 = exp2f(st[sb][0] - mx);
            const float p1 = exp2f(st[sb][1] - mx);
            const float p2 = exp2f(st[sb][2] - mx);
            const float p3 = exp2f(st[sb][3] - mx);
            nl += (p0 + p1) + (p2 + p3);
            u32x2 pw;
            pw.x = pack2bf(p0, p1);
            pw.y = pack2bf(p2, p3);
            *(u32x2*)&pbuf[qi * PSTRU + sb * 8 + grp * 2] = pw;  // P[q][s_local]
        }
        nl += __shfl_xor(nl, 16);
        nl += __shfl_xor(nl, 32);
        l = l * corr + nl;
#pragma unroll
        for (int r = 0; r < 4; ++r) { acc0[r] *= corr; acc1[r] *= corr; }
        // ---- O^T += V^T * P^T  (2 d-blocks x 2 s-chunks of 32)
#pragma unroll
        for (int kk = 0; kk < 2; ++kk) {
            const u32x4 pu = *(const u32x4*)&pbuf[qi * PSTRU + kk * 16 + grp * 4];
            const bfrag pf = __builtin_bit_cast(bfrag, pu);
            const bfrag v0 = *(const bfrag*)(Vp + qi * T_ + s0 + kk * 32 + grp * 8);
            const bfrag v1 = *(const bfrag*)(Vp + (16 + qi) * T_ + s0 + kk * 32 + grp * 8);
            acc0 = __builtin_amdgcn_mfma_f32_16x16x32_bf16(v0, pf, acc0, 0, 0, 0);
            acc1 = __builtin_amdgcn_mfma_f32_16x16x32_bf16(v1, pf, acc1, 0, 0, 0);
        }
    }

    // ---- normalize + write O[b*T+q][h*32 + d]; lane owns q = qbase+qi
    const float rl = 1.f / l;
    float* orow = O + ((size_t)b * T_ + q) * C_ + h * DH_;
    float4 o0, o1;
    o0.x = acc0[0] * rl; o0.y = acc0[1] * rl; o0.z = acc0[2] * rl; o0.w = acc0[3] * rl;
    o1.x = acc1[0] * rl; o1.y = acc1[1] * rl; o1.z = acc1[2] * rl; o1.w = acc1[3] * rl;
    *(float4*)(orow + grp * 4)      = o0;   // d = 0..15 block
    *(float4*)(orow + 16 + grp * 4) = o1;   // d = 16..31 block
}

// ---------------------------------------------------------------------------
// Kernel 3: output projection, in place on O = d_out (fp32).
// ---------------------------------------------------------------------------
__global__ __launch_bounds__(256)
void out_proj(float* __restrict__ O, const float* __restrict__ Wout,
              const float* __restrict__ bout) {
    __shared__ float xs[32 * 128];
    const long rowbase = (long)blockIdx.x * 32;
    const int tid = threadIdx.x;

    const float4* src = (const float4*)(O + rowbase * 128);
    float4* xdst = (float4*)xs;
    for (int i = tid; i < 1024; i += 256) xdst[i] = src[i];
    __syncthreads();

    const int col = tid & 127;
    const int rhalf = tid >> 7;
    float acc[16];
#pragma unroll
    for (int r = 0; r < 16; ++r) acc[r] = 0.f;

    for (int k = 0; k < 128; k += 4) {
        const float w0 = Wout[(k + 0) * 128 + col];
        const float w1 = Wout[(k + 1) * 128 + col];
        const float w2 = Wout[(k + 2) * 128 + col];
        const float w3 = Wout[(k + 3) * 128 + col];
#pragma unroll
        for (int r = 0; r < 16; ++r) {
            const float4 xv = *(const float4*)&xs[(rhalf * 16 + r) * 128 + k];
            acc[r] = fmaf(xv.x, w0, acc[r]);
            acc[r] = fmaf(xv.y, w1, acc[r]);
            acc[r] = fmaf(xv.z, w2, acc[r]);
            acc[r] = fmaf(xv.w, w3, acc[r]);
        }
    }

    const float bias = bout[col];
#pragma unroll
    for (int r = 0; r < 16; ++r) {
        O[(rowbase + rhalf * 16 + r) * C_ + col] = acc[r] + bias;
    }
}

// ---------------------------------------------------------------------------
extern "C" void kernel_launch(void* const* d_in, const int* in_sizes, int n_in,
                              void* d_out, int out_size, void* d_ws, size_t ws_size,
                              hipStream_t stream) {
    const float* x    = (const float*)d_in[0];
    const float* Wqkv = (const float*)d_in[1];
    const float* bqkv = (const float*)d_in[2];
    const float* Wout = (const float*)d_in[3];
    const float* bout = (const float*)d_in[4];
    float* out = (float*)d_out;

    const size_t per = (size_t)BH_ * T_ * DH_;   // 2,097,152 bf16 elems = 4 MB
    __hip_bfloat16* Qb = (__hip_bfloat16*)d_ws;
    __hip_bfloat16* Kb = Qb + per;
    __hip_bfloat16* Vt = Kb + per;

    qkv_proj<<<NTOK / 32, 384, 0, stream>>>(x, Wqkv, bqkv, Qb, Kb, Vt);

    dim3 g2(T_ / 64, BH_);
    attn_mfma<<<g2, 256, 0, stream>>>(Qb, Kb, Vt, out);

    out_proj<<<NTOK / 32, 256, 0, stream>>>(out, Wout, bout);
}

// Round 3
// 117.355 us; speedup vs baseline: 8.9846x; 1.3819x over previous
//
#include <hip/hip_runtime.h>
#include <hip/hip_bf16.h>
#include <math.h>

// Problem constants
#define B_  8
#define T_  2048
#define C_  128
#define H_  4
#define DH_ 32
#define BH_ 32
#define NTOK 16384
// (1/sqrt(32)) * log2(e): scores come out in log2 domain -> softmax via exp2
#define QSCALE_ 0.25503486f

typedef __attribute__((ext_vector_type(8))) __bf16 bfrag;       // 4 VGPRs, MFMA A/B
typedef __attribute__((ext_vector_type(4))) float f32x4;        // MFMA C/D
typedef __attribute__((ext_vector_type(2))) unsigned int u32x2;
typedef __attribute__((ext_vector_type(4))) unsigned int u32x4;

__device__ __forceinline__ unsigned int pack2bf(float a, float b) {
    unsigned int ua = __float_as_uint(a);
    unsigned int ub = __float_as_uint(b);
    ua += 0x7fffu + ((ua >> 16) & 1u);   // RNE to bf16
    ub += 0x7fffu + ((ub >> 16) & 1u);
    return (ua >> 16) | (ub & 0xffff0000u);
}

// ---------------------------------------------------------------------------
// Kernel 1: QKV projection (fp32 math) -> Qb,Kb bf16 [BH][T][32] (Q pre-scaled
// by 1/sqrt(Dh)*log2e), Vt bf16 [BH][32][T] (transposed for MFMA B-fragments).
// ---------------------------------------------------------------------------
__global__ __launch_bounds__(384)
void qkv_proj(const float* __restrict__ x, const float* __restrict__ Wqkv,
              const float* __restrict__ bqkv,
              __hip_bfloat16* __restrict__ Qb, __hip_bfloat16* __restrict__ Kb,
              __hip_bfloat16* __restrict__ Vt) {
    __shared__ float xs[32 * 128];
    const int tid = threadIdx.x;
    const long rowbase = (long)blockIdx.x * 32;

    const float4* xsrc = (const float4*)(x + rowbase * 128);
    float4* xdst = (float4*)xs;
    for (int i = tid; i < 1024; i += 384) xdst[i] = xsrc[i];
    __syncthreads();

    const int col = tid;  // 0..383
    float acc[32];
#pragma unroll
    for (int r = 0; r < 32; ++r) acc[r] = 0.f;

    for (int k = 0; k < 128; k += 4) {
        const float w0 = Wqkv[(k + 0) * 384 + col];
        const float w1 = Wqkv[(k + 1) * 384 + col];
        const float w2 = Wqkv[(k + 2) * 384 + col];
        const float w3 = Wqkv[(k + 3) * 384 + col];
#pragma unroll
        for (int r = 0; r < 32; ++r) {
            const float4 xv = *(const float4*)&xs[r * 128 + k];
            acc[r] = fmaf(xv.x, w0, acc[r]);
            acc[r] = fmaf(xv.y, w1, acc[r]);
            acc[r] = fmaf(xv.z, w2, acc[r]);
            acc[r] = fmaf(xv.w, w3, acc[r]);
        }
    }

    const float bias = bqkv[col];
    const int which = col >> 7;     // 0=Q, 1=K, 2=V
    const int c = col & 127;
    const int h = c >> 5;
    const int d = c & 31;

#pragma unroll
    for (int r = 0; r < 32; ++r) {
        const long row = rowbase + r;
        const long bb = row >> 11;
        const long t  = row & 2047;
        const long bh = bb * H_ + h;
        const float val = acc[r] + bias;
        if (which == 0)      Qb[(bh * T_ + t) * DH_ + d] = __float2bfloat16(val * QSCALE_);
        else if (which == 1) Kb[(bh * T_ + t) * DH_ + d] = __float2bfloat16(val);
        else                 Vt[(bh * DH_ + d) * T_ + t] = __float2bfloat16(val);
    }
}

// ---------------------------------------------------------------------------
// Kernel 2: MFMA flash attention, fixed-max softmax, paired q-chunks.
// Each wave owns TWO 16-row q-chunks: qA = j*64+w*16 (small), qB = (31-j)*64
// + w*16 (large) -> exactly 33 chunk-tiles per wave (perfect balance), and K/V
// fragment loads are shared between both chunks.
// Fixed max m=0 (scores in log2 domain; data-bounded, fp32/bf16 safe):
// no per-tile max reduce, no rescale, no cross-tile serial deps. l is a
// per-lane partial, reduced once at the end.
// ---------------------------------------------------------------------------
#define PSTRU 36   // uint stride per P row (64 bf16 + 8 pad)

__global__ __launch_bounds__(256)
void attn_mfma(const __hip_bfloat16* __restrict__ Qb,
               const __hip_bfloat16* __restrict__ Kb,
               const __hip_bfloat16* __restrict__ Vt,
               float* __restrict__ O) {
    __shared__ unsigned int plds[4][2][16 * PSTRU];

    // block swizzle: XCD gets 4 fixed bh values (L2-resident K/V/Q)
    const int lin  = blockIdx.x;          // 0..511
    const int xcd  = lin & 7;
    const int slot = lin >> 3;            // 0..63
    const int bh   = (xcd << 2) | (slot & 3);
    const int j    = slot >> 2;           // 0..15
    const int b = bh >> 2, h = bh & 3;

    const int tid  = threadIdx.x;
    const int w    = tid >> 6;
    const int lane = tid & 63;
    const int qi   = lane & 15;
    const int grp  = lane >> 4;

    const int qAb = j * 64 + w * 16;
    const int qBb = (31 - j) * 64 + w * 16;
    const int qA = qAb + qi, qB = qBb + qi;

    const __hip_bfloat16* Qp = Qb + (size_t)bh * T_ * DH_;
    const __hip_bfloat16* Kp = Kb + (size_t)bh * T_ * DH_;
    const __hip_bfloat16* Vp = Vt + (size_t)bh * DH_ * T_;

    const bfrag qfA = *(const bfrag*)(Qp + qA * DH_ + grp * 8);
    const bfrag qfB = *(const bfrag*)(Qp + qB * DH_ + grp * 8);

    const f32x4 zero = {0.f, 0.f, 0.f, 0.f};
    f32x4 aA0 = zero, aA1 = zero, aB0 = zero, aB1 = zero;
    float lA = 0.f, lB = 0.f;
    unsigned int* pbA = plds[w][0];
    unsigned int* pbB = plds[w][1];

    const int ntB = 32 - j;   // B tiles; A active while t <= j

    for (int t = 0; t < ntB; ++t) {
        const int s0 = t * 64;
        // shared K fragments for this s-tile
        bfrag kf0 = *(const bfrag*)(Kp + (s0 +  0 + qi) * DH_ + grp * 8);
        bfrag kf1 = *(const bfrag*)(Kp + (s0 + 16 + qi) * DH_ + grp * 8);
        bfrag kf2 = *(const bfrag*)(Kp + (s0 + 32 + qi) * DH_ + grp * 8);
        bfrag kf3 = *(const bfrag*)(Kp + (s0 + 48 + qi) * DH_ + grp * 8);
        // shared V fragments: vf[kk][dblock]
        bfrag v00 = *(const bfrag*)(Vp + qi * T_        + s0      + grp * 8);
        bfrag v01 = *(const bfrag*)(Vp + (16 + qi) * T_ + s0      + grp * 8);
        bfrag v10 = *(const bfrag*)(Vp + qi * T_        + s0 + 32 + grp * 8);
        bfrag v11 = *(const bfrag*)(Vp + (16 + qi) * T_ + s0 + 32 + grp * 8);

        auto chunk = [&](const bfrag& qf, int q, bool band, unsigned int* pbuf,
                         float& lp, f32x4& a0, f32x4& a1) {
            f32x4 st0 = __builtin_amdgcn_mfma_f32_16x16x32_bf16(kf0, qf, zero, 0, 0, 0);
            f32x4 st1 = __builtin_amdgcn_mfma_f32_16x16x32_bf16(kf1, qf, zero, 0, 0, 0);
            f32x4 st2 = __builtin_amdgcn_mfma_f32_16x16x32_bf16(kf2, qf, zero, 0, 0, 0);
            f32x4 st3 = __builtin_amdgcn_mfma_f32_16x16x32_bf16(kf3, qf, zero, 0, 0, 0);
            if (band) {   // wave-uniform; only the diagonal tile
#pragma unroll
                for (int r = 0; r < 4; ++r) {
                    if (s0 +  0 + grp * 4 + r > q) st0[r] = -INFINITY;
                    if (s0 + 16 + grp * 4 + r > q) st1[r] = -INFINITY;
                    if (s0 + 32 + grp * 4 + r > q) st2[r] = -INFINITY;
                    if (s0 + 48 + grp * 4 + r > q) st3[r] = -INFINITY;
                }
            }
            float ls = 0.f;
#pragma unroll
            for (int sb = 0; sb < 4; ++sb) {
                const f32x4 st = (sb == 0) ? st0 : (sb == 1) ? st1 : (sb == 2) ? st2 : st3;
                const float p0 = exp2f(st[0]);
                const float p1 = exp2f(st[1]);
                const float p2 = exp2f(st[2]);
                const float p3 = exp2f(st[3]);
                ls += (p0 + p1) + (p2 + p3);
                u32x2 pw;
                pw.x = pack2bf(p0, p1);
                pw.y = pack2bf(p2, p3);
                *(u32x2*)&pbuf[qi * PSTRU + sb * 8 + grp * 2] = pw;
            }
            lp += ls;
            {
                const u32x4 pu0 = *(const u32x4*)&pbuf[qi * PSTRU + grp * 4];
                const bfrag pf0 = __builtin_bit_cast(bfrag, pu0);
                a0 = __builtin_amdgcn_mfma_f32_16x16x32_bf16(v00, pf0, a0, 0, 0, 0);
                a1 = __builtin_amdgcn_mfma_f32_16x16x32_bf16(v01, pf0, a1, 0, 0, 0);
                const u32x4 pu1 = *(const u32x4*)&pbuf[qi * PSTRU + 16 + grp * 4];
                const bfrag pf1 = __builtin_bit_cast(bfrag, pu1);
                a0 = __builtin_amdgcn_mfma_f32_16x16x32_bf16(v10, pf1, a0, 0, 0, 0);
                a1 = __builtin_amdgcn_mfma_f32_16x16x32_bf16(v11, pf1, a1, 0, 0, 0);
            }
        };

        chunk(qfB, qB, t == ntB - 1, pbB, lB, aB0, aB1);
        if (t <= j) chunk(qfA, qA, t == j, pbA, lA, aA0, aA1);
    }

    // final l reduction (lanes {q, q+16, q+32, q+48} hold quarters)
    lA += __shfl_xor(lA, 16);  lA += __shfl_xor(lA, 32);
    lB += __shfl_xor(lB, 16);  lB += __shfl_xor(lB, 32);

    const float rA = 1.f / lA, rB = 1.f / lB;
    float* orA = O + ((size_t)b * T_ + qA) * C_ + h * DH_;
    float* orB = O + ((size_t)b * T_ + qB) * C_ + h * DH_;
    float4 o;
    o.x = aA0[0] * rA; o.y = aA0[1] * rA; o.z = aA0[2] * rA; o.w = aA0[3] * rA;
    *(float4*)(orA + grp * 4) = o;
    o.x = aA1[0] * rA; o.y = aA1[1] * rA; o.z = aA1[2] * rA; o.w = aA1[3] * rA;
    *(float4*)(orA + 16 + grp * 4) = o;
    o.x = aB0[0] * rB; o.y = aB0[1] * rB; o.z = aB0[2] * rB; o.w = aB0[3] * rB;
    *(float4*)(orB + grp * 4) = o;
    o.x = aB1[0] * rB; o.y = aB1[1] * rB; o.z = aB1[2] * rB; o.w = aB1[3] * rB;
    *(float4*)(orB + 16 + grp * 4) = o;
}

// ---------------------------------------------------------------------------
// Kernel 3: output projection, in place on O = d_out (fp32).
// ---------------------------------------------------------------------------
__global__ __launch_bounds__(256)
void out_proj(float* __restrict__ O, const float* __restrict__ Wout,
              const float* __restrict__ bout) {
    __shared__ float xs[32 * 128];
    const long rowbase = (long)blockIdx.x * 32;
    const int tid = threadIdx.x;

    const float4* src = (const float4*)(O + rowbase * 128);
    float4* xdst = (float4*)xs;
    for (int i = tid; i < 1024; i += 256) xdst[i] = src[i];
    __syncthreads();

    const int col = tid & 127;
    const int rhalf = tid >> 7;
    float acc[16];
#pragma unroll
    for (int r = 0; r < 16; ++r) acc[r] = 0.f;

    for (int k = 0; k < 128; k += 4) {
        const float w0 = Wout[(k + 0) * 128 + col];
        const float w1 = Wout[(k + 1) * 128 + col];
        const float w2 = Wout[(k + 2) * 128 + col];
        const float w3 = Wout[(k + 3) * 128 + col];
#pragma unroll
        for (int r = 0; r < 16; ++r) {
            const float4 xv = *(const float4*)&xs[(rhalf * 16 + r) * 128 + k];
            acc[r] = fmaf(xv.x, w0, acc[r]);
            acc[r] = fmaf(xv.y, w1, acc[r]);
            acc[r] = fmaf(xv.z, w2, acc[r]);
            acc[r] = fmaf(xv.w, w3, acc[r]);
        }
    }

    const float bias = bout[col];
#pragma unroll
    for (int r = 0; r < 16; ++r) {
        O[(rowbase + rhalf * 16 + r) * C_ + col] = acc[r] + bias;
    }
}

// ---------------------------------------------------------------------------
extern "C" void kernel_launch(void* const* d_in, const int* in_sizes, int n_in,
                              void* d_out, int out_size, void* d_ws, size_t ws_size,
                              hipStream_t stream) {
    const float* x    = (const float*)d_in[0];
    const float* Wqkv = (const float*)d_in[1];
    const float* bqkv = (const float*)d_in[2];
    const float* Wout = (const float*)d_in[3];
    const float* bout = (const float*)d_in[4];
    float* out = (float*)d_out;

    const size_t per = (size_t)BH_ * T_ * DH_;   // 2,097,152 bf16 elems = 4 MB
    __hip_bfloat16* Qb = (__hip_bfloat16*)d_ws;
    __hip_bfloat16* Kb = Qb + per;
    __hip_bfloat16* Vt = Kb + per;

    qkv_proj<<<NTOK / 32, 384, 0, stream>>>(x, Wqkv, bqkv, Qb, Kb, Vt);

    attn_mfma<<<512, 256, 0, stream>>>(Qb, Kb, Vt, out);

    out_proj<<<NTOK / 32, 256, 0, stream>>>(out, Wout, bout);
}

// Round 4
// 81.440 us; speedup vs baseline: 12.9468x; 1.4410x over previous
//
#include <hip/hip_runtime.h>
#include <hip/hip_bf16.h>
#include <math.h>

// Problem constants
#define B_  8
#define T_  2048
#define C_  128
#define H_  4
#define DH_ 32
#define BH_ 32
#define NTOK 16384
// (1/sqrt(32)) * log2(e): scores come out in log2 domain -> softmax via exp2
#define QSCALE_ 0.25503486f

typedef __attribute__((ext_vector_type(8))) __bf16 bfrag;       // 4 VGPRs, MFMA A/B
typedef __attribute__((ext_vector_type(4))) float f32x4;        // MFMA C/D
typedef __attribute__((ext_vector_type(2))) unsigned int u32x2;
typedef __attribute__((ext_vector_type(4))) unsigned int u32x4;

__device__ __forceinline__ unsigned int pack2bf(float a, float b) {
    unsigned int ua = __float_as_uint(a);
    unsigned int ub = __float_as_uint(b);
    ua += 0x7fffu + ((ua >> 16) & 1u);   // RNE to bf16
    ub += 0x7fffu + ((ub >> 16) & 1u);
    return (ua >> 16) | (ub & 0xffff0000u);
}

// ---------------------------------------------------------------------------
// Kernel 0: prep — cast x to bf16 [NTOK][128]; transpose Wqkv -> WqkvT bf16
// [384][128]; transpose Wout -> WoutT bf16 [128][128].
// ---------------------------------------------------------------------------
__global__ __launch_bounds__(256)
void prep(const float* __restrict__ x, const float* __restrict__ Wqkv,
          const float* __restrict__ Wout,
          __hip_bfloat16* __restrict__ xb, __hip_bfloat16* __restrict__ WqkvT,
          __hip_bfloat16* __restrict__ WoutT) {
    const int bid = blockIdx.x;
    const int tid = threadIdx.x;
    if (bid < 1024) {
        const size_t e = ((size_t)bid * 256 + tid) * 8;
        const float4 a = *(const float4*)(x + e);
        const float4 b = *(const float4*)(x + e + 4);
        u32x4 pk;
        pk.x = pack2bf(a.x, a.y);
        pk.y = pack2bf(a.z, a.w);
        pk.z = pack2bf(b.x, b.y);
        pk.w = pack2bf(b.z, b.w);
        *(u32x4*)(xb + e) = pk;
    } else if (bid < 1024 + 24) {
        const int idx = (bid - 1024) * 256 + tid;    // 0..6143
        const int n = idx >> 4, k8 = idx & 15;
        float v[8];
#pragma unroll
        for (int i = 0; i < 8; ++i) v[i] = Wqkv[(k8 * 8 + i) * 384 + n];
        u32x4 pk;
        pk.x = pack2bf(v[0], v[1]); pk.y = pack2bf(v[2], v[3]);
        pk.z = pack2bf(v[4], v[5]); pk.w = pack2bf(v[6], v[7]);
        *(u32x4*)(WqkvT + n * 128 + k8 * 8) = pk;
    } else {
        const int idx = (bid - 1048) * 256 + tid;    // 0..2047
        const int n = idx >> 4, k8 = idx & 15;
        float v[8];
#pragma unroll
        for (int i = 0; i < 8; ++i) v[i] = Wout[(k8 * 8 + i) * 128 + n];
        u32x4 pk;
        pk.x = pack2bf(v[0], v[1]); pk.y = pack2bf(v[2], v[3]);
        pk.z = pack2bf(v[4], v[5]); pk.w = pack2bf(v[6], v[7]);
        *(u32x4*)(WoutT + n * 128 + k8 * 8) = pk;
    }
}

// ---------------------------------------------------------------------------
// Kernel 1: MFMA QKV projection. M-tile 16 (grid 1024), 4 waves x 6 n-blocks.
// No LDS: A/B fragments straight from global (xb/WT L2-hot; 16 lanes x 4 grp
// cover full 64B lines). Q/K blocks: mfma(x, W) -> lane owns col (contig d
// writes). V blocks: mfma(W, x) -> lane owns token (contig t writes into
// Vt[bh][d][t]). Bias + Q pre-scale fused.
// ---------------------------------------------------------------------------
__global__ __launch_bounds__(256)
void qkv_mfma(const __hip_bfloat16* __restrict__ xb,
              const __hip_bfloat16* __restrict__ WT,
              const float* __restrict__ bqkv,
              __hip_bfloat16* __restrict__ Qb, __hip_bfloat16* __restrict__ Kb,
              __hip_bfloat16* __restrict__ Vt) {
    const int mbase = blockIdx.x * 16;
    const int w = threadIdx.x >> 6, lane = threadIdx.x & 63;
    const int qi = lane & 15, grp = lane >> 4;

    const f32x4 zero = {0.f, 0.f, 0.f, 0.f};
    f32x4 acc[6] = {zero, zero, zero, zero, zero, zero};

    bfrag xf[4];
#pragma unroll
    for (int ks = 0; ks < 4; ++ks)
        xf[ks] = *(const bfrag*)(xb + (size_t)(mbase + qi) * 128 + ks * 32 + grp * 8);

#pragma unroll
    for (int j = 0; j < 6; ++j) {
        const int nb = j * 4 + w;
#pragma unroll
        for (int ks = 0; ks < 4; ++ks) {
            const bfrag wf = *(const bfrag*)(WT + (size_t)(nb * 16 + qi) * 128 + ks * 32 + grp * 8);
            if (j < 4) acc[j] = __builtin_amdgcn_mfma_f32_16x16x32_bf16(xf[ks], wf, acc[j], 0, 0, 0);
            else       acc[j] = __builtin_amdgcn_mfma_f32_16x16x32_bf16(wf, xf[ks], acc[j], 0, 0, 0);
        }
    }

    const long bb = mbase >> 11;        // batch
    const long tloc = mbase & 2047;     // token within batch
#pragma unroll
    for (int j = 0; j < 6; ++j) {
        const int nb = j * 4 + w;
        if (j < 4) {                    // Q or K columns
            const int c = nb * 16 + qi;
            const float bias = bqkv[c];
            const int h = (c >> 5) & 3, d = c & 31;
            __hip_bfloat16* dst = (c < 128) ? Qb : Kb;
            const float sc = (c < 128) ? QSCALE_ : 1.f;
#pragma unroll
            for (int r = 0; r < 4; ++r) {
                const long t = tloc + grp * 4 + r;
                dst[((bb * H_ + h) * T_ + t) * DH_ + d] =
                    __float2bfloat16((acc[j][r] + bias) * sc);
            }
        } else {                        // V columns (swapped orientation)
            const long t = tloc + qi;
#pragma unroll
            for (int r = 0; r < 4; ++r) {
                const int c = nb * 16 + grp * 4 + r;
                const int local = c - 256;
                const int h = local >> 5, d = local & 31;
                Vt[((bb * H_ + h) * DH_ + d) * T_ + t] =
                    __float2bfloat16(acc[j][r] + bqkv[c]);
            }
        }
    }
}

// ---------------------------------------------------------------------------
// Kernel 2: MFMA flash attention (unchanged structure; writes bf16 O).
// ---------------------------------------------------------------------------
#define PSTRU 36   // uint stride per P row (64 bf16 + 8 pad)

__global__ __launch_bounds__(256)
void attn_mfma(const __hip_bfloat16* __restrict__ Qb,
               const __hip_bfloat16* __restrict__ Kb,
               const __hip_bfloat16* __restrict__ Vt,
               __hip_bfloat16* __restrict__ Ob) {
    __shared__ unsigned int plds[4][2][16 * PSTRU];

    const int lin  = blockIdx.x;          // 0..511
    const int xcd  = lin & 7;
    const int slot = lin >> 3;            // 0..63
    const int bh   = (xcd << 2) | (slot & 3);
    const int j    = slot >> 2;           // 0..15
    const int b = bh >> 2, h = bh & 3;

    const int tid  = threadIdx.x;
    const int w    = tid >> 6;
    const int lane = tid & 63;
    const int qi   = lane & 15;
    const int grp  = lane >> 4;

    const int qAb = j * 64 + w * 16;
    const int qBb = (31 - j) * 64 + w * 16;
    const int qA = qAb + qi, qB = qBb + qi;

    const __hip_bfloat16* Qp = Qb + (size_t)bh * T_ * DH_;
    const __hip_bfloat16* Kp = Kb + (size_t)bh * T_ * DH_;
    const __hip_bfloat16* Vp = Vt + (size_t)bh * DH_ * T_;

    const bfrag qfA = *(const bfrag*)(Qp + qA * DH_ + grp * 8);
    const bfrag qfB = *(const bfrag*)(Qp + qB * DH_ + grp * 8);

    const f32x4 zero = {0.f, 0.f, 0.f, 0.f};
    f32x4 aA0 = zero, aA1 = zero, aB0 = zero, aB1 = zero;
    float lA = 0.f, lB = 0.f;
    unsigned int* pbA = plds[w][0];
    unsigned int* pbB = plds[w][1];

    const int ntB = 32 - j;   // B tiles; A active while t <= j

    for (int t = 0; t < ntB; ++t) {
        const int s0 = t * 64;
        bfrag kf0 = *(const bfrag*)(Kp + (s0 +  0 + qi) * DH_ + grp * 8);
        bfrag kf1 = *(const bfrag*)(Kp + (s0 + 16 + qi) * DH_ + grp * 8);
        bfrag kf2 = *(const bfrag*)(Kp + (s0 + 32 + qi) * DH_ + grp * 8);
        bfrag kf3 = *(const bfrag*)(Kp + (s0 + 48 + qi) * DH_ + grp * 8);
        bfrag v00 = *(const bfrag*)(Vp + qi * T_        + s0      + grp * 8);
        bfrag v01 = *(const bfrag*)(Vp + (16 + qi) * T_ + s0      + grp * 8);
        bfrag v10 = *(const bfrag*)(Vp + qi * T_        + s0 + 32 + grp * 8);
        bfrag v11 = *(const bfrag*)(Vp + (16 + qi) * T_ + s0 + 32 + grp * 8);

        auto chunk = [&](const bfrag& qf, int q, bool band, unsigned int* pbuf,
                         float& lp, f32x4& a0, f32x4& a1) {
            f32x4 st0 = __builtin_amdgcn_mfma_f32_16x16x32_bf16(kf0, qf, zero, 0, 0, 0);
            f32x4 st1 = __builtin_amdgcn_mfma_f32_16x16x32_bf16(kf1, qf, zero, 0, 0, 0);
            f32x4 st2 = __builtin_amdgcn_mfma_f32_16x16x32_bf16(kf2, qf, zero, 0, 0, 0);
            f32x4 st3 = __builtin_amdgcn_mfma_f32_16x16x32_bf16(kf3, qf, zero, 0, 0, 0);
            if (band) {
#pragma unroll
                for (int r = 0; r < 4; ++r) {
                    if (s0 +  0 + grp * 4 + r > q) st0[r] = -INFINITY;
                    if (s0 + 16 + grp * 4 + r > q) st1[r] = -INFINITY;
                    if (s0 + 32 + grp * 4 + r > q) st2[r] = -INFINITY;
                    if (s0 + 48 + grp * 4 + r > q) st3[r] = -INFINITY;
                }
            }
            float ls = 0.f;
#pragma unroll
            for (int sb = 0; sb < 4; ++sb) {
                const f32x4 st = (sb == 0) ? st0 : (sb == 1) ? st1 : (sb == 2) ? st2 : st3;
                const float p0 = exp2f(st[0]);
                const float p1 = exp2f(st[1]);
                const float p2 = exp2f(st[2]);
                const float p3 = exp2f(st[3]);
                ls += (p0 + p1) + (p2 + p3);
                u32x2 pw;
                pw.x = pack2bf(p0, p1);
                pw.y = pack2bf(p2, p3);
                *(u32x2*)&pbuf[qi * PSTRU + sb * 8 + grp * 2] = pw;
            }
            lp += ls;
            {
                const u32x4 pu0 = *(const u32x4*)&pbuf[qi * PSTRU + grp * 4];
                const bfrag pf0 = __builtin_bit_cast(bfrag, pu0);
                a0 = __builtin_amdgcn_mfma_f32_16x16x32_bf16(v00, pf0, a0, 0, 0, 0);
                a1 = __builtin_amdgcn_mfma_f32_16x16x32_bf16(v01, pf0, a1, 0, 0, 0);
                const u32x4 pu1 = *(const u32x4*)&pbuf[qi * PSTRU + 16 + grp * 4];
                const bfrag pf1 = __builtin_bit_cast(bfrag, pu1);
                a0 = __builtin_amdgcn_mfma_f32_16x16x32_bf16(v10, pf1, a0, 0, 0, 0);
                a1 = __builtin_amdgcn_mfma_f32_16x16x32_bf16(v11, pf1, a1, 0, 0, 0);
            }
        };

        chunk(qfB, qB, t == ntB - 1, pbB, lB, aB0, aB1);
        if (t <= j) chunk(qfA, qA, t == j, pbA, lA, aA0, aA1);
    }

    lA += __shfl_xor(lA, 16);  lA += __shfl_xor(lA, 32);
    lB += __shfl_xor(lB, 16);  lB += __shfl_xor(lB, 32);

    const float rA = 1.f / lA, rB = 1.f / lB;
    __hip_bfloat16* orA = Ob + ((size_t)b * T_ + qA) * C_ + h * DH_;
    __hip_bfloat16* orB = Ob + ((size_t)b * T_ + qB) * C_ + h * DH_;
    u32x2 pw;
    pw.x = pack2bf(aA0[0] * rA, aA0[1] * rA); pw.y = pack2bf(aA0[2] * rA, aA0[3] * rA);
    *(u32x2*)(orA + grp * 4) = pw;
    pw.x = pack2bf(aA1[0] * rA, aA1[1] * rA); pw.y = pack2bf(aA1[2] * rA, aA1[3] * rA);
    *(u32x2*)(orA + 16 + grp * 4) = pw;
    pw.x = pack2bf(aB0[0] * rB, aB0[1] * rB); pw.y = pack2bf(aB0[2] * rB, aB0[3] * rB);
    *(u32x2*)(orB + grp * 4) = pw;
    pw.x = pack2bf(aB1[0] * rB, aB1[1] * rB); pw.y = pack2bf(aB1[2] * rB, aB1[3] * rB);
    *(u32x2*)(orB + 16 + grp * 4) = pw;
}

// ---------------------------------------------------------------------------
// Kernel 3: MFMA output projection. Reads bf16 Ob + WoutT, writes fp32 out.
// ---------------------------------------------------------------------------
__global__ __launch_bounds__(256)
void out_mfma(const __hip_bfloat16* __restrict__ Ob,
              const __hip_bfloat16* __restrict__ WT,
              const float* __restrict__ bout, float* __restrict__ out) {
    const int mbase = blockIdx.x * 16;
    const int w = threadIdx.x >> 6, lane = threadIdx.x & 63;
    const int qi = lane & 15, grp = lane >> 4;

    const f32x4 zero = {0.f, 0.f, 0.f, 0.f};
    f32x4 acc[2] = {zero, zero};

    bfrag xf[4];
#pragma unroll
    for (int ks = 0; ks < 4; ++ks)
        xf[ks] = *(const bfrag*)(Ob + (size_t)(mbase + qi) * 128 + ks * 32 + grp * 8);

#pragma unroll
    for (int j = 0; j < 2; ++j) {
        const int nb = j * 4 + w;
#pragma unroll
        for (int ks = 0; ks < 4; ++ks) {
            const bfrag wf = *(const bfrag*)(WT + (size_t)(nb * 16 + qi) * 128 + ks * 32 + grp * 8);
            acc[j] = __builtin_amdgcn_mfma_f32_16x16x32_bf16(xf[ks], wf, acc[j], 0, 0, 0);
        }
    }

#pragma unroll
    for (int j = 0; j < 2; ++j) {
        const int nb = j * 4 + w;
        const int c = nb * 16 + qi;
        const float bias = bout[c];
#pragma unroll
        for (int r = 0; r < 4; ++r)
            out[(size_t)(mbase + grp * 4 + r) * 128 + c] = acc[j][r] + bias;
    }
}

// ---------------------------------------------------------------------------
extern "C" void kernel_launch(void* const* d_in, const int* in_sizes, int n_in,
                              void* d_out, int out_size, void* d_ws, size_t ws_size,
                              hipStream_t stream) {
    const float* x    = (const float*)d_in[0];
    const float* Wqkv = (const float*)d_in[1];
    const float* bqkv = (const float*)d_in[2];
    const float* Wout = (const float*)d_in[3];
    const float* bout = (const float*)d_in[4];
    float* out = (float*)d_out;

    const size_t per = (size_t)BH_ * T_ * DH_;   // 2,097,152 bf16 elems = 4 MB
    __hip_bfloat16* Qb    = (__hip_bfloat16*)d_ws;
    __hip_bfloat16* Kb    = Qb + per;
    __hip_bfloat16* Vt    = Kb + per;
    __hip_bfloat16* xb    = Vt + per;
    __hip_bfloat16* Ob    = xb + per;
    __hip_bfloat16* WqkvT = Ob + per;
    __hip_bfloat16* WoutT = WqkvT + 384 * 128;

    prep<<<1056, 256, 0, stream>>>(x, Wqkv, Wout, xb, WqkvT, WoutT);

    qkv_mfma<<<NTOK / 16, 256, 0, stream>>>(xb, WqkvT, bqkv, Qb, Kb, Vt);

    attn_mfma<<<512, 256, 0, stream>>>(Qb, Kb, Vt, Ob);

    out_mfma<<<NTOK / 16, 256, 0, stream>>>(Ob, WoutT, bout, out);
}

// Round 6
// 80.253 us; speedup vs baseline: 13.1383x; 1.0148x over previous
//
#include <hip/hip_runtime.h>
#include <hip/hip_bf16.h>
#include <math.h>

// Problem constants
#define B_  8
#define T_  2048
#define C_  128
#define H_  4
#define DH_ 32
#define BH_ 32
#define NTOK 16384
// (1/sqrt(32)) * log2(e): scores come out in log2 domain -> softmax via exp2
#define QSCALE_ 0.25503486f

typedef __attribute__((ext_vector_type(8))) __bf16 bfrag;       // 4 VGPRs, MFMA A/B
typedef __attribute__((ext_vector_type(4))) float f32x4;        // MFMA C/D
typedef __attribute__((ext_vector_type(2))) unsigned int u32x2;
typedef __attribute__((ext_vector_type(4))) unsigned int u32x4;

__device__ __forceinline__ unsigned int pack2bf(float a, float b) {
    unsigned int ua = __float_as_uint(a);
    unsigned int ub = __float_as_uint(b);
    ua += 0x7fffu + ((ua >> 16) & 1u);   // RNE to bf16
    ub += 0x7fffu + ((ub >> 16) & 1u);
    return (ua >> 16) | (ub & 0xffff0000u);
}

// alias (bit_cast of __hip_bfloat162 doesn't compile on this toolchain)
__device__ __forceinline__ unsigned int pkbf(float a, float b) {
    return pack2bf(a, b);
}

// ---------------------------------------------------------------------------
// Kernel 0: prep — cast x to bf16 [NTOK][128]; transpose Wqkv -> WqkvT bf16
// [384][128]; transpose Wout -> WoutT bf16 [128][128].
// ---------------------------------------------------------------------------
__global__ __launch_bounds__(256)
void prep(const float* __restrict__ x, const float* __restrict__ Wqkv,
          const float* __restrict__ Wout,
          __hip_bfloat16* __restrict__ xb, __hip_bfloat16* __restrict__ WqkvT,
          __hip_bfloat16* __restrict__ WoutT) {
    const int bid = blockIdx.x;
    const int tid = threadIdx.x;
    if (bid < 1024) {
        const size_t e = ((size_t)bid * 256 + tid) * 8;
        const float4 a = *(const float4*)(x + e);
        const float4 b = *(const float4*)(x + e + 4);
        u32x4 pk;
        pk.x = pack2bf(a.x, a.y);
        pk.y = pack2bf(a.z, a.w);
        pk.z = pack2bf(b.x, b.y);
        pk.w = pack2bf(b.z, b.w);
        *(u32x4*)(xb + e) = pk;
    } else if (bid < 1024 + 24) {
        const int idx = (bid - 1024) * 256 + tid;    // 0..6143
        const int n = idx >> 4, k8 = idx & 15;
        float v[8];
#pragma unroll
        for (int i = 0; i < 8; ++i) v[i] = Wqkv[(k8 * 8 + i) * 384 + n];
        u32x4 pk;
        pk.x = pack2bf(v[0], v[1]); pk.y = pack2bf(v[2], v[3]);
        pk.z = pack2bf(v[4], v[5]); pk.w = pack2bf(v[6], v[7]);
        *(u32x4*)(WqkvT + n * 128 + k8 * 8) = pk;
    } else {
        const int idx = (bid - 1048) * 256 + tid;    // 0..2047
        const int n = idx >> 4, k8 = idx & 15;
        float v[8];
#pragma unroll
        for (int i = 0; i < 8; ++i) v[i] = Wout[(k8 * 8 + i) * 128 + n];
        u32x4 pk;
        pk.x = pack2bf(v[0], v[1]); pk.y = pack2bf(v[2], v[3]);
        pk.z = pack2bf(v[4], v[5]); pk.w = pack2bf(v[6], v[7]);
        *(u32x4*)(WoutT + n * 128 + k8 * 8) = pk;
    }
}

// ---------------------------------------------------------------------------
// Kernel 1: MFMA QKV projection (unchanged from round 4).
// ---------------------------------------------------------------------------
__global__ __launch_bounds__(256)
void qkv_mfma(const __hip_bfloat16* __restrict__ xb,
              const __hip_bfloat16* __restrict__ WT,
              const float* __restrict__ bqkv,
              __hip_bfloat16* __restrict__ Qb, __hip_bfloat16* __restrict__ Kb,
              __hip_bfloat16* __restrict__ Vt) {
    const int mbase = blockIdx.x * 16;
    const int w = threadIdx.x >> 6, lane = threadIdx.x & 63;
    const int qi = lane & 15, grp = lane >> 4;

    const f32x4 zero = {0.f, 0.f, 0.f, 0.f};
    f32x4 acc[6] = {zero, zero, zero, zero, zero, zero};

    bfrag xf[4];
#pragma unroll
    for (int ks = 0; ks < 4; ++ks)
        xf[ks] = *(const bfrag*)(xb + (size_t)(mbase + qi) * 128 + ks * 32 + grp * 8);

#pragma unroll
    for (int j = 0; j < 6; ++j) {
        const int nb = j * 4 + w;
#pragma unroll
        for (int ks = 0; ks < 4; ++ks) {
            const bfrag wf = *(const bfrag*)(WT + (size_t)(nb * 16 + qi) * 128 + ks * 32 + grp * 8);
            if (j < 4) acc[j] = __builtin_amdgcn_mfma_f32_16x16x32_bf16(xf[ks], wf, acc[j], 0, 0, 0);
            else       acc[j] = __builtin_amdgcn_mfma_f32_16x16x32_bf16(wf, xf[ks], acc[j], 0, 0, 0);
        }
    }

    const long bb = mbase >> 11;        // batch
    const long tloc = mbase & 2047;     // token within batch
#pragma unroll
    for (int j = 0; j < 6; ++j) {
        const int nb = j * 4 + w;
        if (j < 4) {                    // Q or K columns
            const int c = nb * 16 + qi;
            const float bias = bqkv[c];
            const int h = (c >> 5) & 3, d = c & 31;
            __hip_bfloat16* dst = (c < 128) ? Qb : Kb;
            const float sc = (c < 128) ? QSCALE_ : 1.f;
#pragma unroll
            for (int r = 0; r < 4; ++r) {
                const long t = tloc + grp * 4 + r;
                dst[((bb * H_ + h) * T_ + t) * DH_ + d] =
                    __float2bfloat16((acc[j][r] + bias) * sc);
            }
        } else {                        // V columns (swapped orientation)
            const long t = tloc + qi;
#pragma unroll
            for (int r = 0; r < 4; ++r) {
                const int c = nb * 16 + grp * 4 + r;
                const int local = c - 256;
                const int h = local >> 5, d = local & 31;
                Vt[((bb * H_ + h) * DH_ + d) * T_ + t] =
                    __float2bfloat16(acc[j][r] + bqkv[c]);
            }
        }
    }
}

// ---------------------------------------------------------------------------
// Kernel 2: MFMA flash attention, 4-way s-split per block.
// Block = one pair of 16-q chunks (p, 127-p) of one bh -> exactly 33
// chunk-tiles, split round-robin over the 4 waves (t = w, w+4, ...).
// Fixed-max softmax (m=0) => cross-wave combine is a plain sum of (acc, l)
// partials, done in LDS (union with the P-buffers; 2 barriers).
// Grid: 2048 blocks = 8192 waves (4x round-4 TLP).
// ---------------------------------------------------------------------------
#define PSTRU 36   // uint stride per P row (64 bf16 + 8 pad)

__global__ __launch_bounds__(256)
void attn_mfma(const __hip_bfloat16* __restrict__ Qb,
               const __hip_bfloat16* __restrict__ Kb,
               const __hip_bfloat16* __restrict__ Vt,
               __hip_bfloat16* __restrict__ Ob) {
    // union: P-buffers u32[4][2][16*PSTRU] = 4608 u32; combine float[4][64][20]
    __shared__ unsigned int smem[5120];   // 20.5 KB

    const int lin  = blockIdx.x;          // 0..2047
    const int xcd  = lin & 7;
    const int slot = lin >> 3;            // 0..255
    const int bh   = (xcd << 2) | (slot & 3);
    const int p    = slot >> 2;           // pair index 0..63
    const int b = bh >> 2, h = bh & 3;

    const int tid  = threadIdx.x;
    const int w    = tid >> 6;
    const int lane = tid & 63;
    const int qi   = lane & 15;
    const int grp  = lane >> 4;

    const int qA = p * 16 + qi;           // small chunk
    const int qB = (127 - p) * 16 + qi;   // large chunk
    const int TA = p >> 2;                // last s-tile for A
    const int TB = (127 - p) >> 2;        // last s-tile for B

    const __hip_bfloat16* Qp = Qb + (size_t)bh * T_ * DH_;
    const __hip_bfloat16* Kp = Kb + (size_t)bh * T_ * DH_;
    const __hip_bfloat16* Vp = Vt + (size_t)bh * DH_ * T_;

    const bfrag qfA = *(const bfrag*)(Qp + qA * DH_ + grp * 8);
    const bfrag qfB = *(const bfrag*)(Qp + qB * DH_ + grp * 8);

    const f32x4 zero = {0.f, 0.f, 0.f, 0.f};
    f32x4 aA0 = zero, aA1 = zero, aB0 = zero, aB1 = zero;
    float lA = 0.f, lB = 0.f;
    unsigned int* pbA = smem + (w * 2 + 0) * (16 * PSTRU);
    unsigned int* pbB = smem + (w * 2 + 1) * (16 * PSTRU);

    for (int t = w; t <= TB; t += 4) {
        const int s0 = t * 64;
        bfrag kf0 = *(const bfrag*)(Kp + (s0 +  0 + qi) * DH_ + grp * 8);
        bfrag kf1 = *(const bfrag*)(Kp + (s0 + 16 + qi) * DH_ + grp * 8);
        bfrag kf2 = *(const bfrag*)(Kp + (s0 + 32 + qi) * DH_ + grp * 8);
        bfrag kf3 = *(const bfrag*)(Kp + (s0 + 48 + qi) * DH_ + grp * 8);
        bfrag v00 = *(const bfrag*)(Vp + qi * T_        + s0      + grp * 8);
        bfrag v01 = *(const bfrag*)(Vp + (16 + qi) * T_ + s0      + grp * 8);
        bfrag v10 = *(const bfrag*)(Vp + qi * T_        + s0 + 32 + grp * 8);
        bfrag v11 = *(const bfrag*)(Vp + (16 + qi) * T_ + s0 + 32 + grp * 8);

        auto chunk = [&](const bfrag& qf, int q, bool band, unsigned int* pbuf,
                         float& lp, f32x4& a0, f32x4& a1) {
            f32x4 st0 = __builtin_amdgcn_mfma_f32_16x16x32_bf16(kf0, qf, zero, 0, 0, 0);
            f32x4 st1 = __builtin_amdgcn_mfma_f32_16x16x32_bf16(kf1, qf, zero, 0, 0, 0);
            f32x4 st2 = __builtin_amdgcn_mfma_f32_16x16x32_bf16(kf2, qf, zero, 0, 0, 0);
            f32x4 st3 = __builtin_amdgcn_mfma_f32_16x16x32_bf16(kf3, qf, zero, 0, 0, 0);
            if (band) {
#pragma unroll
                for (int r = 0; r < 4; ++r) {
                    if (s0 +  0 + grp * 4 + r > q) st0[r] = -INFINITY;
                    if (s0 + 16 + grp * 4 + r > q) st1[r] = -INFINITY;
                    if (s0 + 32 + grp * 4 + r > q) st2[r] = -INFINITY;
                    if (s0 + 48 + grp * 4 + r > q) st3[r] = -INFINITY;
                }
            }
            float ls = 0.f;
#pragma unroll
            for (int sb = 0; sb < 4; ++sb) {
                const f32x4 st = (sb == 0) ? st0 : (sb == 1) ? st1 : (sb == 2) ? st2 : st3;
                const float p0 = exp2f(st[0]);
                const float p1 = exp2f(st[1]);
                const float p2 = exp2f(st[2]);
                const float p3 = exp2f(st[3]);
                ls += (p0 + p1) + (p2 + p3);
                u32x2 pw;
                pw.x = pkbf(p0, p1);
                pw.y = pkbf(p2, p3);
                *(u32x2*)&pbuf[qi * PSTRU + sb * 8 + grp * 2] = pw;
            }
            lp += ls;
            {
                const u32x4 pu0 = *(const u32x4*)&pbuf[qi * PSTRU + grp * 4];
                const bfrag pf0 = __builtin_bit_cast(bfrag, pu0);
                a0 = __builtin_amdgcn_mfma_f32_16x16x32_bf16(v00, pf0, a0, 0, 0, 0);
                a1 = __builtin_amdgcn_mfma_f32_16x16x32_bf16(v01, pf0, a1, 0, 0, 0);
                const u32x4 pu1 = *(const u32x4*)&pbuf[qi * PSTRU + 16 + grp * 4];
                const bfrag pf1 = __builtin_bit_cast(bfrag, pu1);
                a0 = __builtin_amdgcn_mfma_f32_16x16x32_bf16(v10, pf1, a0, 0, 0, 0);
                a1 = __builtin_amdgcn_mfma_f32_16x16x32_bf16(v11, pf1, a1, 0, 0, 0);
            }
        };

        chunk(qfB, qB, t == TB, pbB, lB, aB0, aB1);
        if (t <= TA) chunk(qfA, qA, t == TA, pbA, lA, aA0, aA1);
    }

    // reduce l across the 4 grp lanes sharing each qi
    lA += __shfl_xor(lA, 16);  lA += __shfl_xor(lA, 32);
    lB += __shfl_xor(lB, 16);  lB += __shfl_xor(lB, 32);

    // cross-wave combine: all waves done with P-buffers before reuse as floats
    __syncthreads();
    float* csm = (float*)smem;            // [4][64][20]
    float* my = csm + (w * 64 + lane) * 20;
    *(f32x4*)(my +  0) = aA0;
    *(f32x4*)(my +  4) = aA1;
    *(f32x4*)(my +  8) = aB0;
    *(f32x4*)(my + 12) = aB1;
    my[16] = lA;  my[17] = lB;
    __syncthreads();

    if (w == 0) {
#pragma unroll
        for (int ww = 1; ww < 4; ++ww) {
            const float* o = csm + (ww * 64 + lane) * 20;
            const f32x4 q0 = *(const f32x4*)(o + 0);
            const f32x4 q1 = *(const f32x4*)(o + 4);
            const f32x4 q2 = *(const f32x4*)(o + 8);
            const f32x4 q3 = *(const f32x4*)(o + 12);
#pragma unroll
            for (int r = 0; r < 4; ++r) {
                aA0[r] += q0[r]; aA1[r] += q1[r];
                aB0[r] += q2[r]; aB1[r] += q3[r];
            }
            lA += o[16];  lB += o[17];
        }
        const float rA = 1.f / lA, rB = 1.f / lB;
        __hip_bfloat16* orA = Ob + ((size_t)b * T_ + qA) * C_ + h * DH_;
        __hip_bfloat16* orB = Ob + ((size_t)b * T_ + qB) * C_ + h * DH_;
        u32x2 pw;
        pw.x = pkbf(aA0[0] * rA, aA0[1] * rA); pw.y = pkbf(aA0[2] * rA, aA0[3] * rA);
        *(u32x2*)(orA + grp * 4) = pw;
        pw.x = pkbf(aA1[0] * rA, aA1[1] * rA); pw.y = pkbf(aA1[2] * rA, aA1[3] * rA);
        *(u32x2*)(orA + 16 + grp * 4) = pw;
        pw.x = pkbf(aB0[0] * rB, aB0[1] * rB); pw.y = pkbf(aB0[2] * rB, aB0[3] * rB);
        *(u32x2*)(orB + grp * 4) = pw;
        pw.x = pkbf(aB1[0] * rB, aB1[1] * rB); pw.y = pkbf(aB1[2] * rB, aB1[3] * rB);
        *(u32x2*)(orB + 16 + grp * 4) = pw;
    }
}

// ---------------------------------------------------------------------------
// Kernel 3: MFMA output projection (unchanged from round 4).
// ---------------------------------------------------------------------------
__global__ __launch_bounds__(256)
void out_mfma(const __hip_bfloat16* __restrict__ Ob,
              const __hip_bfloat16* __restrict__ WT,
              const float* __restrict__ bout, float* __restrict__ out) {
    const int mbase = blockIdx.x * 16;
    const int w = threadIdx.x >> 6, lane = threadIdx.x & 63;
    const int qi = lane & 15, grp = lane >> 4;

    const f32x4 zero = {0.f, 0.f, 0.f, 0.f};
    f32x4 acc[2] = {zero, zero};

    bfrag xf[4];
#pragma unroll
    for (int ks = 0; ks < 4; ++ks)
        xf[ks] = *(const bfrag*)(Ob + (size_t)(mbase + qi) * 128 + ks * 32 + grp * 8);

#pragma unroll
    for (int j = 0; j < 2; ++j) {
        const int nb = j * 4 + w;
#pragma unroll
        for (int ks = 0; ks < 4; ++ks) {
            const bfrag wf = *(const bfrag*)(WT + (size_t)(nb * 16 + qi) * 128 + ks * 32 + grp * 8);
            acc[j] = __builtin_amdgcn_mfma_f32_16x16x32_bf16(xf[ks], wf, acc[j], 0, 0, 0);
        }
    }

#pragma unroll
    for (int j = 0; j < 2; ++j) {
        const int nb = j * 4 + w;
        const int c = nb * 16 + qi;
        const float bias = bout[c];
#pragma unroll
        for (int r = 0; r < 4; ++r)
            out[(size_t)(mbase + grp * 4 + r) * 128 + c] = acc[j][r] + bias;
    }
}

// ---------------------------------------------------------------------------
extern "C" void kernel_launch(void* const* d_in, const int* in_sizes, int n_in,
                              void* d_out, int out_size, void* d_ws, size_t ws_size,
                              hipStream_t stream) {
    const float* x    = (const float*)d_in[0];
    const float* Wqkv = (const float*)d_in[1];
    const float* bqkv = (const float*)d_in[2];
    const float* Wout = (const float*)d_in[3];
    const float* bout = (const float*)d_in[4];
    float* out = (float*)d_out;

    const size_t per = (size_t)BH_ * T_ * DH_;   // 2,097,152 bf16 elems = 4 MB
    __hip_bfloat16* Qb    = (__hip_bfloat16*)d_ws;
    __hip_bfloat16* Kb    = Qb + per;
    __hip_bfloat16* Vt    = Kb + per;
    __hip_bfloat16* xb    = Vt + per;
    __hip_bfloat16* Ob    = xb + per;
    __hip_bfloat16* WqkvT = Ob + per;
    __hip_bfloat16* WoutT = WqkvT + 384 * 128;

    prep<<<1056, 256, 0, stream>>>(x, Wqkv, Wout, xb, WqkvT, WoutT);

    qkv_mfma<<<NTOK / 16, 256, 0, stream>>>(xb, WqkvT, bqkv, Qb, Kb, Vt);

    attn_mfma<<<2048, 256, 0, stream>>>(Qb, Kb, Vt, Ob);

    out_mfma<<<NTOK / 16, 256, 0, stream>>>(Ob, WoutT, bout, out);
}

// Round 7
// 70.548 us; speedup vs baseline: 14.9456x; 1.1376x over previous
//
#include <hip/hip_runtime.h>
#include <hip/hip_bf16.h>
#include <math.h>

// Problem constants
#define B_  8
#define T_  2048
#define C_  128
#define H_  4
#define DH_ 32
#define BH_ 32
#define NTOK 16384
// (1/sqrt(32)) * log2(e): scores come out in log2 domain -> softmax via exp2
#define QSCALE_ 0.25503486f

typedef __attribute__((ext_vector_type(8))) __bf16 bfrag;        // 4 VGPRs, MFMA A/B
typedef __attribute__((ext_vector_type(4))) float f32x4;
typedef __attribute__((ext_vector_type(16))) float f32x16;       // 32x32 MFMA C/D
typedef __attribute__((ext_vector_type(2))) unsigned int u32x2;
typedef __attribute__((ext_vector_type(4))) unsigned int u32x4;

__device__ __forceinline__ unsigned int pack2bf(float a, float b) {
    unsigned int ua = __float_as_uint(a);
    unsigned int ub = __float_as_uint(b);
    ua += 0x7fffu + ((ua >> 16) & 1u);   // RNE to bf16
    ub += 0x7fffu + ((ub >> 16) & 1u);
    return (ua >> 16) | (ub & 0xffff0000u);
}

// single-instruction packed f32x2 -> bf16x2 (no builtin on gfx950)
__device__ __forceinline__ unsigned int cvtpk_bf16(float lo, float hi) {
    unsigned int r;
    asm("v_cvt_pk_bf16_f32 %0, %1, %2" : "=v"(r) : "v"(lo), "v"(hi));
    return r;
}

// ---------------------------------------------------------------------------
// Kernel 0: prep — cast x to bf16 [NTOK][128]; transpose Wqkv -> WqkvT bf16
// [384][128]; transpose Wout -> WoutT bf16 [128][128].
// ---------------------------------------------------------------------------
__global__ __launch_bounds__(256)
void prep(const float* __restrict__ x, const float* __restrict__ Wqkv,
          const float* __restrict__ Wout,
          __hip_bfloat16* __restrict__ xb, __hip_bfloat16* __restrict__ WqkvT,
          __hip_bfloat16* __restrict__ WoutT) {
    const int bid = blockIdx.x;
    const int tid = threadIdx.x;
    if (bid < 1024) {
        const size_t e = ((size_t)bid * 256 + tid) * 8;
        const float4 a = *(const float4*)(x + e);
        const float4 b = *(const float4*)(x + e + 4);
        u32x4 pk;
        pk.x = pack2bf(a.x, a.y);
        pk.y = pack2bf(a.z, a.w);
        pk.z = pack2bf(b.x, b.y);
        pk.w = pack2bf(b.z, b.w);
        *(u32x4*)(xb + e) = pk;
    } else if (bid < 1024 + 24) {
        const int idx = (bid - 1024) * 256 + tid;    // 0..6143
        const int n = idx >> 4, k8 = idx & 15;
        float v[8];
#pragma unroll
        for (int i = 0; i < 8; ++i) v[i] = Wqkv[(k8 * 8 + i) * 384 + n];
        u32x4 pk;
        pk.x = pack2bf(v[0], v[1]); pk.y = pack2bf(v[2], v[3]);
        pk.z = pack2bf(v[4], v[5]); pk.w = pack2bf(v[6], v[7]);
        *(u32x4*)(WqkvT + n * 128 + k8 * 8) = pk;
    } else {
        const int idx = (bid - 1048) * 256 + tid;    // 0..2047
        const int n = idx >> 4, k8 = idx & 15;
        float v[8];
#pragma unroll
        for (int i = 0; i < 8; ++i) v[i] = Wout[(k8 * 8 + i) * 128 + n];
        u32x4 pk;
        pk.x = pack2bf(v[0], v[1]); pk.y = pack2bf(v[2], v[3]);
        pk.z = pack2bf(v[4], v[5]); pk.w = pack2bf(v[6], v[7]);
        *(u32x4*)(WoutT + n * 128 + k8 * 8) = pk;
    }
}

// ---------------------------------------------------------------------------
// Kernel 1: MFMA QKV projection (unchanged).
// ---------------------------------------------------------------------------
__global__ __launch_bounds__(256)
void qkv_mfma(const __hip_bfloat16* __restrict__ xb,
              const __hip_bfloat16* __restrict__ WT,
              const float* __restrict__ bqkv,
              __hip_bfloat16* __restrict__ Qb, __hip_bfloat16* __restrict__ Kb,
              __hip_bfloat16* __restrict__ Vt) {
    const int mbase = blockIdx.x * 16;
    const int w = threadIdx.x >> 6, lane = threadIdx.x & 63;
    const int qi = lane & 15, grp = lane >> 4;

    const f32x4 zero = {0.f, 0.f, 0.f, 0.f};
    f32x4 acc[6] = {zero, zero, zero, zero, zero, zero};

    bfrag xf[4];
#pragma unroll
    for (int ks = 0; ks < 4; ++ks)
        xf[ks] = *(const bfrag*)(xb + (size_t)(mbase + qi) * 128 + ks * 32 + grp * 8);

#pragma unroll
    for (int j = 0; j < 6; ++j) {
        const int nb = j * 4 + w;
#pragma unroll
        for (int ks = 0; ks < 4; ++ks) {
            const bfrag wf = *(const bfrag*)(WT + (size_t)(nb * 16 + qi) * 128 + ks * 32 + grp * 8);
            if (j < 4) acc[j] = __builtin_amdgcn_mfma_f32_16x16x32_bf16(xf[ks], wf, acc[j], 0, 0, 0);
            else       acc[j] = __builtin_amdgcn_mfma_f32_16x16x32_bf16(wf, xf[ks], acc[j], 0, 0, 0);
        }
    }

    const long bb = mbase >> 11;        // batch
    const long tloc = mbase & 2047;     // token within batch
#pragma unroll
    for (int j = 0; j < 6; ++j) {
        const int nb = j * 4 + w;
        if (j < 4) {                    // Q or K columns
            const int c = nb * 16 + qi;
            const float bias = bqkv[c];
            const int h = (c >> 5) & 3, d = c & 31;
            __hip_bfloat16* dst = (c < 128) ? Qb : Kb;
            const float sc = (c < 128) ? QSCALE_ : 1.f;
#pragma unroll
            for (int r = 0; r < 4; ++r) {
                const long t = tloc + grp * 4 + r;
                dst[((bb * H_ + h) * T_ + t) * DH_ + d] =
                    __float2bfloat16((acc[j][r] + bias) * sc);
            }
        } else {                        // V columns (swapped orientation)
            const long t = tloc + qi;
#pragma unroll
            for (int r = 0; r < 4; ++r) {
                const int c = nb * 16 + grp * 4 + r;
                const int local = c - 256;
                const int h = local >> 5, d = local & 31;
                Vt[((bb * H_ + h) * DH_ + d) * T_ + t] =
                    __float2bfloat16(acc[j][r] + bqkv[c]);
            }
        }
    }
}

// ---------------------------------------------------------------------------
// Kernel 2: flash attention, 32x32x16 MFMA, in-register P path.
// Block = pair of 32-q chunks (p, 63-p) of one bh -> 33 s-tiles of 64,
// split round-robin over 4 waves. Swapped QK^T: lane owns q = lane&31,
// holds 16 of 32 s per C-tile (crow(r,hi)). P -> bf16 via v_cvt_pk_bf16_f32,
// redistributed lane-locally via permlane32_swap -> PV B-frags, NO LDS.
// Fixed-max softmax (m=0): cross-wave combine = plain sum in LDS at the end.
// ---------------------------------------------------------------------------
__global__ __launch_bounds__(256)
void attn_mfma(const __hip_bfloat16* __restrict__ Qb,
               const __hip_bfloat16* __restrict__ Kb,
               const __hip_bfloat16* __restrict__ Vt,
               __hip_bfloat16* __restrict__ Ob) {
    __shared__ float csm[4 * 64 * 17];    // 17.4 KB combine buffer

    const int lin  = blockIdx.x;          // 0..1023
    const int xcd  = lin & 7;
    const int slot = lin >> 3;            // 0..127
    const int bh   = (xcd << 2) | (slot & 3);
    const int p    = slot >> 2;           // pair 0..31
    const int b = bh >> 2, h = bh & 3;

    const int w    = threadIdx.x >> 6;
    const int lane = threadIdx.x & 63;
    const int ql   = lane & 31;           // q within chunk (C col) / MFMA row
    const int hi   = lane >> 5;
    const int hi4  = hi * 4;
    const int hi8  = hi * 8;

    const int cA = p, cB = 63 - p;
    const int qA = cA * 32 + ql, qB = cB * 32 + ql;
    const int TA = (cA * 32 + 31) >> 6;   // last s-tile for chunk A
    const int TB = (cB * 32 + 31) >> 6;

    const __hip_bfloat16* Qp = Qb + (size_t)bh * T_ * DH_;
    const __hip_bfloat16* Kp = Kb + (size_t)bh * T_ * DH_;
    const __hip_bfloat16* Vp = Vt + (size_t)bh * DH_ * T_;

    // Q B-frags: [kh] -> d-slice kh*16 + hi*8 .. +8
    const bfrag qA0 = *(const bfrag*)(Qp + qA * DH_ + hi8);
    const bfrag qA1 = *(const bfrag*)(Qp + qA * DH_ + 16 + hi8);
    const bfrag qB0 = *(const bfrag*)(Qp + qB * DH_ + hi8);
    const bfrag qB1 = *(const bfrag*)(Qp + qB * DH_ + 16 + hi8);

    f32x16 oA, oB, z16;
#pragma unroll
    for (int r = 0; r < 16; ++r) { oA[r] = 0.f; oB[r] = 0.f; z16[r] = 0.f; }
    float lA = 0.f, lB = 0.f;

    for (int t = w; t <= TB; t += 4) {
        const bool doA = (t <= TA);
#pragma unroll
        for (int sub = 0; sub < 2; ++sub) {
            const int sbase = t * 64 + sub * 32;
            // K A-frags (rows s, k=d) and V A-frags (rows d, k=s) -- shared A/B
            const bfrag kf0 = *(const bfrag*)(Kp + (sbase + ql) * DH_ + hi8);
            const bfrag kf1 = *(const bfrag*)(Kp + (sbase + ql) * DH_ + 16 + hi8);
            const bfrag vf0 = *(const bfrag*)(Vp + ql * T_ + sbase + hi8);
            const bfrag vf1 = *(const bfrag*)(Vp + ql * T_ + sbase + 16 + hi8);

            auto proc = [&](const bfrag& qf0, const bfrag& qf1, int qg, bool band,
                            f32x16& oacc, float& lacc) {
                f32x16 s = __builtin_amdgcn_mfma_f32_32x32x16_bf16(kf0, qf0, z16, 0, 0, 0);
                s = __builtin_amdgcn_mfma_f32_32x32x16_bf16(kf1, qf1, s, 0, 0, 0);
                if (band) {
#pragma unroll
                    for (int r = 0; r < 16; ++r) {
                        const int srow = sbase + (r & 3) + 8 * (r >> 2) + hi4;
                        if (srow > qg) s[r] = -INFINITY;
                    }
                }
                float pp[16];
                float ls = 0.f;
#pragma unroll
                for (int r = 0; r < 16; ++r) { pp[r] = exp2f(s[r]); ls += pp[r]; }
                lacc += ls;
                // pack r0..7 -> P-frag for s[sbase..+16), r8..15 -> s[sbase+16..+32)
                u32x4 w0, w1;
                {
                    unsigned a0 = cvtpk_bf16(pp[0], pp[1]);
                    unsigned a1 = cvtpk_bf16(pp[2], pp[3]);
                    unsigned a2 = cvtpk_bf16(pp[4], pp[5]);
                    unsigned a3 = cvtpk_bf16(pp[6], pp[7]);
                    auto r02 = __builtin_amdgcn_permlane32_swap((int)a0, (int)a2, false, false);
                    auto r13 = __builtin_amdgcn_permlane32_swap((int)a1, (int)a3, false, false);
                    w0.x = (unsigned)r02[0]; w0.y = (unsigned)r13[0];
                    w0.z = (unsigned)r02[1]; w0.w = (unsigned)r13[1];
                }
                {
                    unsigned a0 = cvtpk_bf16(pp[8],  pp[9]);
                    unsigned a1 = cvtpk_bf16(pp[10], pp[11]);
                    unsigned a2 = cvtpk_bf16(pp[12], pp[13]);
                    unsigned a3 = cvtpk_bf16(pp[14], pp[15]);
                    auto r02 = __builtin_amdgcn_permlane32_swap((int)a0, (int)a2, false, false);
                    auto r13 = __builtin_amdgcn_permlane32_swap((int)a1, (int)a3, false, false);
                    w1.x = (unsigned)r02[0]; w1.y = (unsigned)r13[0];
                    w1.z = (unsigned)r02[1]; w1.w = (unsigned)r13[1];
                }
                oacc = __builtin_amdgcn_mfma_f32_32x32x16_bf16(
                            vf0, __builtin_bit_cast(bfrag, w0), oacc, 0, 0, 0);
                oacc = __builtin_amdgcn_mfma_f32_32x32x16_bf16(
                            vf1, __builtin_bit_cast(bfrag, w1), oacc, 0, 0, 0);
            };

            proc(qB0, qB1, qB, t == TB, oB, lB);
            if (doA) proc(qA0, qA1, qA, t == TA, oA, lA);
        }
    }

    // merge the two hi-halves' l (same q, disjoint s)
    lA += __shfl_xor(lA, 32);
    lB += __shfl_xor(lB, 32);

    float* my = csm + (w * 64 + lane) * 17;

    // ---- phase A: store, reduce across waves, write
    {
        f32x4 t0 = {oA[0], oA[1], oA[2], oA[3]};
        f32x4 t1 = {oA[4], oA[5], oA[6], oA[7]};
        f32x4 t2 = {oA[8], oA[9], oA[10], oA[11]};
        f32x4 t3 = {oA[12], oA[13], oA[14], oA[15]};
        *(f32x4*)(my + 0) = t0;  *(f32x4*)(my + 4) = t1;
        *(f32x4*)(my + 8) = t2;  *(f32x4*)(my + 12) = t3;
        my[16] = lA;
    }
    __syncthreads();
    if (w == 0) {
#pragma unroll
        for (int ww = 1; ww < 4; ++ww) {
            const float* o = csm + (ww * 64 + lane) * 17;
#pragma unroll
            for (int r = 0; r < 16; ++r) oA[r] += o[r];
            lA += o[16];
        }
        const float rl = 1.f / lA;
        __hip_bfloat16* orow = Ob + ((size_t)b * T_ + qA) * C_ + h * DH_;
#pragma unroll
        for (int g = 0; g < 4; ++g) {
            u32x2 pw;
            pw.x = pack2bf(oA[g * 4 + 0] * rl, oA[g * 4 + 1] * rl);
            pw.y = pack2bf(oA[g * 4 + 2] * rl, oA[g * 4 + 3] * rl);
            *(u32x2*)(orow + 8 * g + hi4) = pw;
        }
    }
    __syncthreads();
    // ---- phase B
    {
        f32x4 t0 = {oB[0], oB[1], oB[2], oB[3]};
        f32x4 t1 = {oB[4], oB[5], oB[6], oB[7]};
        f32x4 t2 = {oB[8], oB[9], oB[10], oB[11]};
        f32x4 t3 = {oB[12], oB[13], oB[14], oB[15]};
        *(f32x4*)(my + 0) = t0;  *(f32x4*)(my + 4) = t1;
        *(f32x4*)(my + 8) = t2;  *(f32x4*)(my + 12) = t3;
        my[16] = lB;
    }
    __syncthreads();
    if (w == 0) {
#pragma unroll
        for (int ww = 1; ww < 4; ++ww) {
            const float* o = csm + (ww * 64 + lane) * 17;
#pragma unroll
            for (int r = 0; r < 16; ++r) oB[r] += o[r];
            lB += o[16];
        }
        const float rl = 1.f / lB;
        __hip_bfloat16* orow = Ob + ((size_t)b * T_ + qB) * C_ + h * DH_;
#pragma unroll
        for (int g = 0; g < 4; ++g) {
            u32x2 pw;
            pw.x = pack2bf(oB[g * 4 + 0] * rl, oB[g * 4 + 1] * rl);
            pw.y = pack2bf(oB[g * 4 + 2] * rl, oB[g * 4 + 3] * rl);
            *(u32x2*)(orow + 8 * g + hi4) = pw;
        }
    }
}

// ---------------------------------------------------------------------------
// Kernel 3: MFMA output projection (unchanged).
// ---------------------------------------------------------------------------
__global__ __launch_bounds__(256)
void out_mfma(const __hip_bfloat16* __restrict__ Ob,
              const __hip_bfloat16* __restrict__ WT,
              const float* __restrict__ bout, float* __restrict__ out) {
    const int mbase = blockIdx.x * 16;
    const int w = threadIdx.x >> 6, lane = threadIdx.x & 63;
    const int qi = lane & 15, grp = lane >> 4;

    const f32x4 zero = {0.f, 0.f, 0.f, 0.f};
    f32x4 acc[2] = {zero, zero};

    bfrag xf[4];
#pragma unroll
    for (int ks = 0; ks < 4; ++ks)
        xf[ks] = *(const bfrag*)(Ob + (size_t)(mbase + qi) * 128 + ks * 32 + grp * 8);

#pragma unroll
    for (int j = 0; j < 2; ++j) {
        const int nb = j * 4 + w;
#pragma unroll
        for (int ks = 0; ks < 4; ++ks) {
            const bfrag wf = *(const bfrag*)(WT + (size_t)(nb * 16 + qi) * 128 + ks * 32 + grp * 8);
            acc[j] = __builtin_amdgcn_mfma_f32_16x16x32_bf16(xf[ks], wf, acc[j], 0, 0, 0);
        }
    }

#pragma unroll
    for (int j = 0; j < 2; ++j) {
        const int nb = j * 4 + w;
        const int c = nb * 16 + qi;
        const float bias = bout[c];
#pragma unroll
        for (int r = 0; r < 4; ++r)
            out[(size_t)(mbase + grp * 4 + r) * 128 + c] = acc[j][r] + bias;
    }
}

// ---------------------------------------------------------------------------
extern "C" void kernel_launch(void* const* d_in, const int* in_sizes, int n_in,
                              void* d_out, int out_size, void* d_ws, size_t ws_size,
                              hipStream_t stream) {
    const float* x    = (const float*)d_in[0];
    const float* Wqkv = (const float*)d_in[1];
    const float* bqkv = (const float*)d_in[2];
    const float* Wout = (const float*)d_in[3];
    const float* bout = (const float*)d_in[4];
    float* out = (float*)d_out;

    const size_t per = (size_t)BH_ * T_ * DH_;   // 2,097,152 bf16 elems = 4 MB
    __hip_bfloat16* Qb    = (__hip_bfloat16*)d_ws;
    __hip_bfloat16* Kb    = Qb + per;
    __hip_bfloat16* Vt    = Kb + per;
    __hip_bfloat16* xb    = Vt + per;
    __hip_bfloat16* Ob    = xb + per;
    __hip_bfloat16* WqkvT = Ob + per;
    __hip_bfloat16* WoutT = WqkvT + 384 * 128;

    prep<<<1056, 256, 0, stream>>>(x, Wqkv, Wout, xb, WqkvT, WoutT);

    qkv_mfma<<<NTOK / 16, 256, 0, stream>>>(xb, WqkvT, bqkv, Qb, Kb, Vt);

    attn_mfma<<<1024, 256, 0, stream>>>(Qb, Kb, Vt, Ob);

    out_mfma<<<NTOK / 16, 256, 0, stream>>>(Ob, WoutT, bout, out);
}

// Round 8
// 69.016 us; speedup vs baseline: 15.2774x; 1.0222x over previous
//
#include <hip/hip_runtime.h>
#include <hip/hip_bf16.h>
#include <math.h>

// Problem constants
#define B_  8
#define T_  2048
#define C_  128
#define H_  4
#define DH_ 32
#define BH_ 32
#define NTOK 16384
// (1/sqrt(32)) * log2(e): scores come out in log2 domain -> softmax via exp2
#define QSCALE_ 0.25503486f

typedef __attribute__((ext_vector_type(8))) __bf16 bfrag;        // 4 VGPRs, MFMA A/B
typedef __attribute__((ext_vector_type(4))) float f32x4;
typedef __attribute__((ext_vector_type(16))) float f32x16;       // 32x32 MFMA C/D
typedef __attribute__((ext_vector_type(2))) unsigned int u32x2;
typedef __attribute__((ext_vector_type(4))) unsigned int u32x4;

__device__ __forceinline__ unsigned int pack2bf(float a, float b) {
    unsigned int ua = __float_as_uint(a);
    unsigned int ub = __float_as_uint(b);
    ua += 0x7fffu + ((ua >> 16) & 1u);   // RNE to bf16
    ub += 0x7fffu + ((ub >> 16) & 1u);
    return (ua >> 16) | (ub & 0xffff0000u);
}

// single-instruction packed f32x2 -> bf16x2 (no builtin on gfx950)
__device__ __forceinline__ unsigned int cvtpk_bf16(float lo, float hi) {
    unsigned int r;
    asm("v_cvt_pk_bf16_f32 %0, %1, %2" : "=v"(r) : "v"(lo), "v"(hi));
    return r;
}

// raw v_exp_f32 (2^x) -- avoids OCML exp2f fixup sequence
__device__ __forceinline__ float fast_exp2(float x) {
    float r;
    asm("v_exp_f32 %0, %1" : "=v"(r) : "v"(x));
    return r;
}

// ---------------------------------------------------------------------------
// Kernel 0: prep — cast x to bf16 [NTOK][128]; transpose Wqkv -> WqkvT bf16
// [384][128]; transpose Wout -> WoutT bf16 [128][128].
// ---------------------------------------------------------------------------
__global__ __launch_bounds__(256)
void prep(const float* __restrict__ x, const float* __restrict__ Wqkv,
          const float* __restrict__ Wout,
          __hip_bfloat16* __restrict__ xb, __hip_bfloat16* __restrict__ WqkvT,
          __hip_bfloat16* __restrict__ WoutT) {
    const int bid = blockIdx.x;
    const int tid = threadIdx.x;
    if (bid < 1024) {
        const size_t e = ((size_t)bid * 256 + tid) * 8;
        const float4 a = *(const float4*)(x + e);
        const float4 b = *(const float4*)(x + e + 4);
        u32x4 pk;
        pk.x = pack2bf(a.x, a.y);
        pk.y = pack2bf(a.z, a.w);
        pk.z = pack2bf(b.x, b.y);
        pk.w = pack2bf(b.z, b.w);
        *(u32x4*)(xb + e) = pk;
    } else if (bid < 1024 + 24) {
        const int idx = (bid - 1024) * 256 + tid;    // 0..6143
        const int n = idx >> 4, k8 = idx & 15;
        float v[8];
#pragma unroll
        for (int i = 0; i < 8; ++i) v[i] = Wqkv[(k8 * 8 + i) * 384 + n];
        u32x4 pk;
        pk.x = pack2bf(v[0], v[1]); pk.y = pack2bf(v[2], v[3]);
        pk.z = pack2bf(v[4], v[5]); pk.w = pack2bf(v[6], v[7]);
        *(u32x4*)(WqkvT + n * 128 + k8 * 8) = pk;
    } else {
        const int idx = (bid - 1048) * 256 + tid;    // 0..2047
        const int n = idx >> 4, k8 = idx & 15;
        float v[8];
#pragma unroll
        for (int i = 0; i < 8; ++i) v[i] = Wout[(k8 * 8 + i) * 128 + n];
        u32x4 pk;
        pk.x = pack2bf(v[0], v[1]); pk.y = pack2bf(v[2], v[3]);
        pk.z = pack2bf(v[4], v[5]); pk.w = pack2bf(v[6], v[7]);
        *(u32x4*)(WoutT + n * 128 + k8 * 8) = pk;
    }
}

// ---------------------------------------------------------------------------
// Kernel 1: MFMA QKV projection, vectorized stores.
// Q/K (j<4): SWAPPED mfma(wf,xf) -> lane owns token, regs = 4 consecutive
//   cols -> one 8B store per j. V (j>=4): mfma(xf,wf) -> lane owns col d,
//   regs = 4 consecutive tokens -> one 8B store into Vt[d][t].
// ---------------------------------------------------------------------------
__global__ __launch_bounds__(256)
void qkv_mfma(const __hip_bfloat16* __restrict__ xb,
              const __hip_bfloat16* __restrict__ WT,
              const float* __restrict__ bqkv,
              __hip_bfloat16* __restrict__ Qb, __hip_bfloat16* __restrict__ Kb,
              __hip_bfloat16* __restrict__ Vt) {
    const int mbase = blockIdx.x * 16;
    const int w = threadIdx.x >> 6, lane = threadIdx.x & 63;
    const int qi = lane & 15, grp = lane >> 4;

    const f32x4 zero = {0.f, 0.f, 0.f, 0.f};
    f32x4 acc[6] = {zero, zero, zero, zero, zero, zero};

    bfrag xf[4];
#pragma unroll
    for (int ks = 0; ks < 4; ++ks)
        xf[ks] = *(const bfrag*)(xb + (size_t)(mbase + qi) * 128 + ks * 32 + grp * 8);

#pragma unroll
    for (int j = 0; j < 6; ++j) {
        const int nb = j * 4 + w;
#pragma unroll
        for (int ks = 0; ks < 4; ++ks) {
            const bfrag wf = *(const bfrag*)(WT + (size_t)(nb * 16 + qi) * 128 + ks * 32 + grp * 8);
            if (j < 4) acc[j] = __builtin_amdgcn_mfma_f32_16x16x32_bf16(wf, xf[ks], acc[j], 0, 0, 0);
            else       acc[j] = __builtin_amdgcn_mfma_f32_16x16x32_bf16(xf[ks], wf, acc[j], 0, 0, 0);
        }
    }

    const long bb = mbase >> 11;        // batch
    const long tloc = mbase & 2047;     // token within batch

    // Q/K: lane owns token t = tloc+qi, regs are cols c0..c0+3
#pragma unroll
    for (int j = 0; j < 4; ++j) {
        const int nb = j * 4 + w;
        const int c0 = nb * 16 + grp * 4;
        const float4 bias = *(const float4*)&bqkv[c0];
        const int local = c0 & 127;
        const int h = local >> 5, d0 = local & 31;
        __hip_bfloat16* dst = (j < 2) ? Qb : Kb;
        const float sc = (j < 2) ? QSCALE_ : 1.f;
        const long t = tloc + qi;
        u32x2 pw;
        pw.x = pack2bf((acc[j][0] + bias.x) * sc, (acc[j][1] + bias.y) * sc);
        pw.y = pack2bf((acc[j][2] + bias.z) * sc, (acc[j][3] + bias.w) * sc);
        *(u32x2*)&dst[((bb * H_ + h) * T_ + t) * DH_ + d0] = pw;
    }
    // V: lane owns col c, regs are tokens tloc+grp*4 .. +3
#pragma unroll
    for (int j = 4; j < 6; ++j) {
        const int nb = j * 4 + w;
        const int c = nb * 16 + qi;
        const int local = c - 256;
        const int h = local >> 5, d = local & 31;
        const float bias = bqkv[c];
        u32x2 pw;
        pw.x = pack2bf(acc[j][0] + bias, acc[j][1] + bias);
        pw.y = pack2bf(acc[j][2] + bias, acc[j][3] + bias);
        *(u32x2*)&Vt[((bb * H_ + h) * DH_ + d) * T_ + tloc + grp * 4] = pw;
    }
}

// ---------------------------------------------------------------------------
// Kernel 2: flash attention, 32x32x16 MFMA, in-register P path,
// 2-deep register ping-pong prefetch over the (tile, sub) sequence.
// ---------------------------------------------------------------------------
__global__ __launch_bounds__(256)
void attn_mfma(const __hip_bfloat16* __restrict__ Qb,
               const __hip_bfloat16* __restrict__ Kb,
               const __hip_bfloat16* __restrict__ Vt,
               __hip_bfloat16* __restrict__ Ob) {
    __shared__ float csm[4 * 64 * 17];    // 17.4 KB combine buffer

    const int lin  = blockIdx.x;          // 0..1023
    const int xcd  = lin & 7;
    const int slot = lin >> 3;            // 0..127
    const int bh   = (xcd << 2) | (slot & 3);
    const int p    = slot >> 2;           // pair 0..31
    const int b = bh >> 2, h = bh & 3;

    const int w    = threadIdx.x >> 6;
    const int lane = threadIdx.x & 63;
    const int ql   = lane & 31;           // q within chunk / MFMA row
    const int hi   = lane >> 5;
    const int hi4  = hi * 4;
    const int hi8  = hi * 8;

    const int cA = p, cB = 63 - p;
    const int qA = cA * 32 + ql, qB = cB * 32 + ql;
    const int TA = (cA * 32 + 31) >> 6;
    const int TB = (cB * 32 + 31) >> 6;

    const __hip_bfloat16* Qp = Qb + (size_t)bh * T_ * DH_;
    const __hip_bfloat16* Kp = Kb + (size_t)bh * T_ * DH_;
    const __hip_bfloat16* Vp = Vt + (size_t)bh * DH_ * T_;

    const bfrag qA0 = *(const bfrag*)(Qp + qA * DH_ + hi8);
    const bfrag qA1 = *(const bfrag*)(Qp + qA * DH_ + 16 + hi8);
    const bfrag qB0 = *(const bfrag*)(Qp + qB * DH_ + hi8);
    const bfrag qB1 = *(const bfrag*)(Qp + qB * DH_ + 16 + hi8);

    f32x16 oA, oB, z16;
#pragma unroll
    for (int r = 0; r < 16; ++r) { oA[r] = 0.f; oB[r] = 0.f; z16[r] = 0.f; }
    float lA = 0.f, lB = 0.f;

    auto ldK = [&](int sbase, bfrag& k0, bfrag& k1, bfrag& v0, bfrag& v1) {
        k0 = *(const bfrag*)(Kp + (sbase + ql) * DH_ + hi8);
        k1 = *(const bfrag*)(Kp + (sbase + ql) * DH_ + 16 + hi8);
        v0 = *(const bfrag*)(Vp + ql * T_ + sbase + hi8);
        v1 = *(const bfrag*)(Vp + ql * T_ + sbase + 16 + hi8);
    };

    auto proc = [&](const bfrag& kf0, const bfrag& kf1, const bfrag& vf0, const bfrag& vf1,
                    int sbase, const bfrag& qf0, const bfrag& qf1, int qg, bool band,
                    f32x16& oacc, float& lacc) {
        f32x16 s = __builtin_amdgcn_mfma_f32_32x32x16_bf16(kf0, qf0, z16, 0, 0, 0);
        s = __builtin_amdgcn_mfma_f32_32x32x16_bf16(kf1, qf1, s, 0, 0, 0);
        if (band) {
#pragma unroll
            for (int r = 0; r < 16; ++r) {
                const int srow = sbase + (r & 3) + 8 * (r >> 2) + hi4;
                if (srow > qg) s[r] = -INFINITY;
            }
        }
        float pp[16];
        float ls = 0.f;
#pragma unroll
        for (int r = 0; r < 16; ++r) { pp[r] = fast_exp2(s[r]); ls += pp[r]; }
        lacc += ls;
        u32x4 w0, w1;
        {
            unsigned a0 = cvtpk_bf16(pp[0], pp[1]);
            unsigned a1 = cvtpk_bf16(pp[2], pp[3]);
            unsigned a2 = cvtpk_bf16(pp[4], pp[5]);
            unsigned a3 = cvtpk_bf16(pp[6], pp[7]);
            auto r02 = __builtin_amdgcn_permlane32_swap((int)a0, (int)a2, false, false);
            auto r13 = __builtin_amdgcn_permlane32_swap((int)a1, (int)a3, false, false);
            w0.x = (unsigned)r02[0]; w0.y = (unsigned)r13[0];
            w0.z = (unsigned)r02[1]; w0.w = (unsigned)r13[1];
        }
        {
            unsigned a0 = cvtpk_bf16(pp[8],  pp[9]);
            unsigned a1 = cvtpk_bf16(pp[10], pp[11]);
            unsigned a2 = cvtpk_bf16(pp[12], pp[13]);
            unsigned a3 = cvtpk_bf16(pp[14], pp[15]);
            auto r02 = __builtin_amdgcn_permlane32_swap((int)a0, (int)a2, false, false);
            auto r13 = __builtin_amdgcn_permlane32_swap((int)a1, (int)a3, false, false);
            w1.x = (unsigned)r02[0]; w1.y = (unsigned)r13[0];
            w1.z = (unsigned)r02[1]; w1.w = (unsigned)r13[1];
        }
        oacc = __builtin_amdgcn_mfma_f32_32x32x16_bf16(
                    vf0, __builtin_bit_cast(bfrag, w0), oacc, 0, 0, 0);
        oacc = __builtin_amdgcn_mfma_f32_32x32x16_bf16(
                    vf1, __builtin_bit_cast(bfrag, w1), oacc, 0, 0, 0);
    };

    // ping-pong prefetch: buf0 = sub0 frags, buf1 = sub1 frags
    bfrag ck0, ck1, cv0, cv1, nk0, nk1, nv0, nv1;
    ldK(w * 64, ck0, ck1, cv0, cv1);   // w <= 3 <= TB always

    for (int t = w; t <= TB; t += 4) {
        const bool doA = (t <= TA);
        const bool bandA = (t == TA);
        const bool bandB = (t == TB);
        const int s0 = t * 64;
        // prefetch sub1 of this tile
        ldK(s0 + 32, nk0, nk1, nv0, nv1);
        // compute sub0
        proc(ck0, ck1, cv0, cv1, s0, qB0, qB1, qB, bandB, oB, lB);
        if (doA) proc(ck0, ck1, cv0, cv1, s0, qA0, qA1, qA, bandA, oA, lA);
        // prefetch sub0 of next tile
        if (t + 4 <= TB) ldK(s0 + 256, ck0, ck1, cv0, cv1);
        // compute sub1
        proc(nk0, nk1, nv0, nv1, s0 + 32, qB0, qB1, qB, bandB, oB, lB);
        if (doA) proc(nk0, nk1, nv0, nv1, s0 + 32, qA0, qA1, qA, bandA, oA, lA);
    }

    // merge the two hi-halves' l (same q, disjoint s)
    lA += __shfl_xor(lA, 32);
    lB += __shfl_xor(lB, 32);

    float* my = csm + (w * 64 + lane) * 17;

    // ---- phase A
    {
        f32x4 t0 = {oA[0], oA[1], oA[2], oA[3]};
        f32x4 t1 = {oA[4], oA[5], oA[6], oA[7]};
        f32x4 t2 = {oA[8], oA[9], oA[10], oA[11]};
        f32x4 t3 = {oA[12], oA[13], oA[14], oA[15]};
        *(f32x4*)(my + 0) = t0;  *(f32x4*)(my + 4) = t1;
        *(f32x4*)(my + 8) = t2;  *(f32x4*)(my + 12) = t3;
        my[16] = lA;
    }
    __syncthreads();
    if (w == 0) {
#pragma unroll
        for (int ww = 1; ww < 4; ++ww) {
            const float* o = csm + (ww * 64 + lane) * 17;
#pragma unroll
            for (int r = 0; r < 16; ++r) oA[r] += o[r];
            lA += o[16];
        }
        const float rl = 1.f / lA;
        __hip_bfloat16* orow = Ob + ((size_t)b * T_ + qA) * C_ + h * DH_;
#pragma unroll
        for (int g = 0; g < 4; ++g) {
            u32x2 pw;
            pw.x = pack2bf(oA[g * 4 + 0] * rl, oA[g * 4 + 1] * rl);
            pw.y = pack2bf(oA[g * 4 + 2] * rl, oA[g * 4 + 3] * rl);
            *(u32x2*)(orow + 8 * g + hi4) = pw;
        }
    }
    __syncthreads();
    // ---- phase B
    {
        f32x4 t0 = {oB[0], oB[1], oB[2], oB[3]};
        f32x4 t1 = {oB[4], oB[5], oB[6], oB[7]};
        f32x4 t2 = {oB[8], oB[9], oB[10], oB[11]};
        f32x4 t3 = {oB[12], oB[13], oB[14], oB[15]};
        *(f32x4*)(my + 0) = t0;  *(f32x4*)(my + 4) = t1;
        *(f32x4*)(my + 8) = t2;  *(f32x4*)(my + 12) = t3;
        my[16] = lB;
    }
    __syncthreads();
    if (w == 0) {
#pragma unroll
        for (int ww = 1; ww < 4; ++ww) {
            const float* o = csm + (ww * 64 + lane) * 17;
#pragma unroll
            for (int r = 0; r < 16; ++r) oB[r] += o[r];
            lB += o[16];
        }
        const float rl = 1.f / lB;
        __hip_bfloat16* orow = Ob + ((size_t)b * T_ + qB) * C_ + h * DH_;
#pragma unroll
        for (int g = 0; g < 4; ++g) {
            u32x2 pw;
            pw.x = pack2bf(oB[g * 4 + 0] * rl, oB[g * 4 + 1] * rl);
            pw.y = pack2bf(oB[g * 4 + 2] * rl, oB[g * 4 + 3] * rl);
            *(u32x2*)(orow + 8 * g + hi4) = pw;
        }
    }
}

// ---------------------------------------------------------------------------
// Kernel 3: MFMA output projection, swapped orientation -> float4 stores.
// ---------------------------------------------------------------------------
__global__ __launch_bounds__(256)
void out_mfma(const __hip_bfloat16* __restrict__ Ob,
              const __hip_bfloat16* __restrict__ WT,
              const float* __restrict__ bout, float* __restrict__ out) {
    const int mbase = blockIdx.x * 16;
    const int w = threadIdx.x >> 6, lane = threadIdx.x & 63;
    const int qi = lane & 15, grp = lane >> 4;

    const f32x4 zero = {0.f, 0.f, 0.f, 0.f};
    f32x4 acc[2] = {zero, zero};

    bfrag xf[4];
#pragma unroll
    for (int ks = 0; ks < 4; ++ks)
        xf[ks] = *(const bfrag*)(Ob + (size_t)(mbase + qi) * 128 + ks * 32 + grp * 8);

#pragma unroll
    for (int j = 0; j < 2; ++j) {
        const int nb = j * 4 + w;
#pragma unroll
        for (int ks = 0; ks < 4; ++ks) {
            const bfrag wf = *(const bfrag*)(WT + (size_t)(nb * 16 + qi) * 128 + ks * 32 + grp * 8);
            acc[j] = __builtin_amdgcn_mfma_f32_16x16x32_bf16(wf, xf[ks], acc[j], 0, 0, 0);
        }
    }

    const int row = mbase + qi;
#pragma unroll
    for (int j = 0; j < 2; ++j) {
        const int nb = j * 4 + w;
        const int c0 = nb * 16 + grp * 4;
        const float4 bias = *(const float4*)&bout[c0];
        float4 o;
        o.x = acc[j][0] + bias.x;  o.y = acc[j][1] + bias.y;
        o.z = acc[j][2] + bias.z;  o.w = acc[j][3] + bias.w;
        *(float4*)&out[(size_t)row * 128 + c0] = o;
    }
}

// ---------------------------------------------------------------------------
extern "C" void kernel_launch(void* const* d_in, const int* in_sizes, int n_in,
                              void* d_out, int out_size, void* d_ws, size_t ws_size,
                              hipStream_t stream) {
    const float* x    = (const float*)d_in[0];
    const float* Wqkv = (const float*)d_in[1];
    const float* bqkv = (const float*)d_in[2];
    const float* Wout = (const float*)d_in[3];
    const float* bout = (const float*)d_in[4];
    float* out = (float*)d_out;

    const size_t per = (size_t)BH_ * T_ * DH_;   // 2,097,152 bf16 elems = 4 MB
    __hip_bfloat16* Qb    = (__hip_bfloat16*)d_ws;
    __hip_bfloat16* Kb    = Qb + per;
    __hip_bfloat16* Vt    = Kb + per;
    __hip_bfloat16* xb    = Vt + per;
    __hip_bfloat16* Ob    = xb + per;
    __hip_bfloat16* WqkvT = Ob + per;
    __hip_bfloat16* WoutT = WqkvT + 384 * 128;

    prep<<<1056, 256, 0, stream>>>(x, Wqkv, Wout, xb, WqkvT, WoutT);

    qkv_mfma<<<NTOK / 16, 256, 0, stream>>>(xb, WqkvT, bqkv, Qb, Kb, Vt);

    attn_mfma<<<1024, 256, 0, stream>>>(Qb, Kb, Vt, Ob);

    out_mfma<<<NTOK / 16, 256, 0, stream>>>(Ob, WoutT, bout, out);
}